// Round 11
// baseline (454.141 us; speedup 1.0000x reference)
//
#include <hip/hip_runtime.h>

// ---------------------------------------------------------------------------
// Round 11: fix R10's branch-2 corruption -- A-frag direct-global loads strided
// by KP while vb2 rows are FP=48 wide (branch1 FP==KP masked the bug). Loader
// now strides by FP and zero-fills K-offsets >= FP (the KP zero-pad zone).
// All other R10 structure kept (fused gather+self-add bf16 vb, no-LDS MFMA,
// 8-deep gather ILP, windowed CSR, merged dual-branch launches).
// ---------------------------------------------------------------------------

static constexpr int NG  = 256;   // graphs
static constexpr int CHK = 4096;  // edges per (chunk,window) block

typedef short  short8  __attribute__((ext_vector_type(8)));
typedef float  floatx4 __attribute__((ext_vector_type(4)));

__device__ __forceinline__ short f2bf(float f) {
    unsigned u = __float_as_uint(f);
    u += 0x7fff + ((u >> 16) & 1);          // RNE to bf16
    return (short)(u >> 16);
}
__device__ __forceinline__ float bf_lo(unsigned u) { return __uint_as_float(u << 16); }
__device__ __forceinline__ float bf_hi(unsigned u) { return __uint_as_float(u & 0xffff0000u); }

static inline int cdiv(int a, int b) { return (a + b - 1) / b; }

// ---- graph offsets via binary search (batch sorted), both branches --------
__global__ void offs_both_kernel(const int* __restrict__ s1, int n1, int* __restrict__ o1,
                                 const int* __restrict__ s2, int n2, int* __restrict__ o2) {
    int t = blockIdx.x * 256 + threadIdx.x;
    int br = t >> 9;
    int g = t & 511;
    if (br > 1 || g > NG) return;
    const int* seg = br ? s2 : s1;
    int N = br ? n2 : n1;
    int* offs = br ? o2 : o1;
    int lo = 0, hi = N;
    while (lo < hi) {
        int mid = (lo + hi) >> 1;
        if (seg[mid] < g) lo = mid + 1; else hi = mid;
    }
    offs[g] = lo;
}

// ---- windowed degree histogram (XCD-affine: window = bid & 7) -------------
__device__ __forceinline__ void deg_win_dev(const int* __restrict__ ei, int E, int N,
                                            int* __restrict__ deg, int bid) {
    int win = bid & 7, chunk = bid >> 3;
    int e0 = chunk * CHK;
    int e1 = e0 + CHK; if (e1 > E) e1 = E;
    int wlo = (int)((long)win * N / 8);
    int whi = (int)((long)(win + 1) * N / 8);
    for (int e = e0 + threadIdx.x; e < e1; e += 256) {
        int dst = ei[E + e];
        if (dst >= wlo && dst < whi) atomicAdd(&deg[dst], 1);
    }
}

__global__ __launch_bounds__(256) void deg_win_both_kernel(
        const int* ei1, int E1, int N1, int* d1, int nblk1,
        const int* ei2, int E2, int N2, int* d2) {
    int bid = blockIdx.x;
    if (bid < nblk1) deg_win_dev(ei1, E1, N1, d1, bid);
    else             deg_win_dev(ei2, E2, N2, d2, bid - nblk1);
}

// ---- prefix scans ---------------------------------------------------------
__global__ __launch_bounds__(256) void scan1_both_kernel(
        const int* __restrict__ d1, int N1, int* __restrict__ x1, int* __restrict__ bs1, int nb1,
        const int* __restrict__ d2, int N2, int* __restrict__ x2, int* __restrict__ bs2) {
    __shared__ int sh[256];
    const int* deg; int* excl; int* bsum; int N; int blk;
    if ((int)blockIdx.x < nb1) { deg = d1; excl = x1; bsum = bs1; N = N1; blk = blockIdx.x; }
    else { deg = d2; excl = x2; bsum = bs2; N = N2; blk = blockIdx.x - nb1; }
    int base = blk * 1024;
    int t = threadIdx.x;
    int v[4];
    int s = 0;
    #pragma unroll
    for (int i = 0; i < 4; ++i) {
        int idx = base + t * 4 + i;
        v[i] = s;
        s += (idx < N) ? deg[idx] : 0;
    }
    sh[t] = s;
    __syncthreads();
    for (int off = 1; off < 256; off <<= 1) {
        int xv = (t >= off) ? sh[t - off] : 0;
        __syncthreads();
        sh[t] += xv;
        __syncthreads();
    }
    int texcl = (t > 0) ? sh[t - 1] : 0;
    #pragma unroll
    for (int i = 0; i < 4; ++i) {
        int idx = base + t * 4 + i;
        if (idx < N) excl[idx] = texcl + v[i];
    }
    if (t == 255) bsum[blk] = sh[255];
}

__global__ void scan2_both_kernel(int* __restrict__ b1, int nb1,
                                  int* __restrict__ b2, int nb2) {
    if (threadIdx.x) return;
    int* b = blockIdx.x ? b2 : b1;
    int nb = blockIdx.x ? nb2 : nb1;
    int acc = 0;
    for (int i = 0; i < nb; ++i) { int t = b[i]; b[i] = acc; acc += t; }
}

__global__ void scan3_both_kernel(int* __restrict__ x1, const int* __restrict__ bs1,
                                  int* __restrict__ c1, int N1, int Ev1,
                                  int* __restrict__ x2, const int* __restrict__ bs2,
                                  int* __restrict__ c2, int N2, int Ev2, int nc1) {
    int bid = blockIdx.x;
    int* excl; const int* bsum; int* cur; int N, E, i;
    if (bid < nc1) { i = bid * 256 + threadIdx.x; excl = x1; bsum = bs1; cur = c1; N = N1; E = Ev1; }
    else { i = (bid - nc1) * 256 + threadIdx.x; excl = x2; bsum = bs2; cur = c2; N = N2; E = Ev2; }
    if (i < N) {
        int v = excl[i] + bsum[i >> 10];
        excl[i] = v;
        cur[i] = v;
    }
    if (i == 0) excl[N] = E;
}

// ---- windowed CSR fill (XCD-affine) ---------------------------------------
__device__ __forceinline__ void fill_win_dev(const int* __restrict__ ei, int E, int N,
                                             int* __restrict__ cursor, int* __restrict__ csr,
                                             int bid) {
    int win = bid & 7, chunk = bid >> 3;
    int e0 = chunk * CHK;
    int e1 = e0 + CHK; if (e1 > E) e1 = E;
    int wlo = (int)((long)win * N / 8);
    int whi = (int)((long)(win + 1) * N / 8);
    for (int e = e0 + threadIdx.x; e < e1; e += 256) {
        int dst = ei[E + e];
        if (dst >= wlo && dst < whi) {
            int pos = atomicAdd(&cursor[dst], 1);
            csr[pos] = ei[e];
        }
    }
}

__global__ __launch_bounds__(256) void fill_win_both_kernel(
        const int* ei1, int E1, int N1, int* c1, int* s1, int nblk1,
        const int* ei2, int E2, int N2, int* c2, int* s2) {
    int bid = blockIdx.x;
    if (bid < nblk1) fill_win_dev(ei1, E1, N1, c1, s1, bid);
    else             fill_win_dev(ei2, E2, N2, c2, s2, bid - nblk1);
}

// ---- unified weight repack via LDS transpose tile -------------------------
struct RJob { const float* W; short* Wb; int K, Nsrc, Ndst, KP; };
struct RJobs10 { RJob j[10]; };

__global__ __launch_bounds__(256) void repack_all_kernel(RJobs10 jobs) {
    __shared__ __align__(16) short sh[64][72];
    RJob jb = jobs.j[blockIdx.y];
    int tilesC = (jb.Ndst + 63) >> 6;
    int tilesK = (jb.KP + 63) >> 6;
    if ((int)blockIdx.x >= tilesC * tilesK) return;
    int c0 = ((int)blockIdx.x % tilesC) * 64;
    int k0 = ((int)blockIdx.x / tilesC) * 64;
    int t = threadIdx.x;
    #pragma unroll 4
    for (int idx = t; idx < 64 * 64; idx += 256) {
        int kk = idx >> 6, cc = idx & 63;
        int k = k0 + kk, cg = c0 + cc;
        float v = (k < jb.K && cg < jb.Nsrc) ? jb.W[(size_t)k * jb.Nsrc + cg] : 0.f;
        sh[cc][kk] = f2bf(v);
    }
    __syncthreads();
    int kt = jb.KP - k0; if (kt > 64) kt = 64;
    int chunks = kt >> 3;
    for (int idx = t; idx < 64 * chunks; idx += 256) {
        int cc = idx / chunks, ch = idx - cc * chunks;
        int cg = c0 + cc;
        if (cg < jb.Ndst) {
            uint4 v = *(const uint4*)&sh[cc][ch * 8];
            *(uint4*)&jb.Wb[(size_t)cg * jb.KP + k0 + ch * 8] = v;
        }
    }
}

// ---- cast both inputs to bf16 padded rows ---------------------------------
__global__ __launch_bounds__(256) void cast_both_kernel(
        const float* __restrict__ x1, unsigned short* __restrict__ xb1, int N1,
        const float* __restrict__ x2, unsigned short* __restrict__ xb2, int N2) {
    int idx = blockIdx.x * 256 + threadIdx.x;
    int tot1 = N1 * 96;
    if (idx < tot1) {
        int n = idx / 96, k = idx - n * 96;
        float v = (k < 93) ? x1[(size_t)n * 93 + k] : 0.f;
        xb1[idx] = (unsigned short)f2bf(v);
    } else {
        idx -= tot1;
        if (idx < N2 * 48) {
            int n = idx / 48, k = idx - n * 48;
            float v = (k < 43) ? x2[(size_t)n * 43 + k] : 0.f;
            xb2[idx] = (unsigned short)f2bf(v);
        }
    }
}

// ---- gather + GIN self-add: vb[n] = bf16(src[n] + sum_{e: dst==n} src[e]) -
template<int FP, int GROUPS>
__device__ __forceinline__ void gather_dev(
        const unsigned short* __restrict__ src, const int* __restrict__ csr,
        const int* __restrict__ ro, unsigned short* __restrict__ vb, int N, int bid) {
    int wave = (bid * 256 + threadIdx.x) >> 6;
    int lane = threadIdx.x & 63;
    if (wave >= N) return;
    constexpr int HW = FP / 2;
    const unsigned* base = (const unsigned*)src;
    unsigned* out = (unsigned*)vb;
    int s = ro[wave], e = ro[wave + 1];
    int grp, l;
    if (GROUPS == 2) { grp = lane >> 5; l = lane & 31; }
    else             { grp = 0;         l = lane;      }
    bool act = l < HW;
    unsigned su = (act && grp == 0) ? base[(size_t)wave * HW + l] : 0u;
    float lo = bf_lo(su), hi = bf_hi(su);        // self term (GIN eps=0)
    int i = s + grp;
    if (GROUPS == 1) {
        for (; i + 7 < e; i += 8) {
            unsigned u[8];
            #pragma unroll
            for (int q = 0; q < 8; ++q)
                u[q] = act ? base[(size_t)csr[i + q] * HW + l] : 0u;
            #pragma unroll
            for (int q = 0; q < 8; ++q) { lo += bf_lo(u[q]); hi += bf_hi(u[q]); }
        }
        for (; i < e; ++i) {
            unsigned u0 = act ? base[(size_t)csr[i] * HW + l] : 0u;
            lo += bf_lo(u0); hi += bf_hi(u0);
        }
    } else {
        for (; i + 6 < e; i += 8) {              // per group: i, i+2, i+4, i+6
            unsigned u[4];
            #pragma unroll
            for (int q = 0; q < 4; ++q)
                u[q] = act ? base[(size_t)csr[i + 2 * q] * HW + l] : 0u;
            #pragma unroll
            for (int q = 0; q < 4; ++q) { lo += bf_lo(u[q]); hi += bf_hi(u[q]); }
        }
        for (; i < e; i += 2) {
            unsigned u0 = act ? base[(size_t)csr[i] * HW + l] : 0u;
            lo += bf_lo(u0); hi += bf_hi(u0);
        }
        lo += __shfl_xor(lo, 32, 64);
        hi += __shfl_xor(hi, 32, 64);
    }
    if (grp == 0 && act) {
        unsigned plo = (unsigned)(unsigned short)f2bf(lo);
        unsigned phi = (unsigned)(unsigned short)f2bf(hi);
        out[(size_t)wave * HW + l] = (phi << 16) | plo;
    }
}

__global__ __launch_bounds__(256) void gather_both_kernel(
        const unsigned short* s1, const int* csr1, const int* ro1,
        unsigned short* vb1, int N1, int nblk1,
        const unsigned short* s2, const int* csr2, const int* ro2,
        unsigned short* vb2, int N2) {
    int bid = blockIdx.x;
    if (bid < nblk1) gather_dev<96, 1>(s1, csr1, ro1, vb1, N1, bid);
    else             gather_dev<48, 2>(s2, csr2, ro2, vb2, N2, bid - nblk1);
}

// ---- A-frag loader from global vb rows (stride FP, zero-fill k >= FP) -----
// BUG FIX vs R10: stride is FP (row width), NOT KP; offsets landing in the
// KP zero-pad zone (>= FP) are materialized as zero instead of read.
template<int FP, int KP, int KK>
__device__ __forceinline__ void load_afr(const short* __restrict__ vr,
                                         int row0, int ln, int quad,
                                         short8 afr[][4]) {
    #pragma unroll
    for (int ms = 0; ms < 4; ++ms) {
        const short* rp = vr + (size_t)(row0 + ms * 16 + ln) * FP;
        #pragma unroll
        for (int kk = 0; kk < KK; ++kk) {
            int offk = kk * 32 + quad * 8;
            short8 v = {0, 0, 0, 0, 0, 0, 0, 0};
            if (FP == KP || offk + 8 <= FP)      // FP==KP folds at compile time
                v = *(const short8*)(rp + offk);
            afr[kk][ms] = v;
        }
    }
}

// ---- GIN layer 1 MFMA, A-frags direct from global vb ----------------------
template<int F, int KP, int NT, int FP>
__device__ __forceinline__ void gin_linear_dev(
        const unsigned short* __restrict__ vb, const short* __restrict__ Wb,
        const float* __restrict__ b, unsigned short* __restrict__ h1b,
        int N, int blk) {
    constexpr int KK = KP / 32;
    int c0 = blk * 64;
    int tid = threadIdx.x;
    int wid = tid >> 6;
    int lane = tid & 63;
    int ln = lane & 15, quad = lane >> 4;
    int cvalid = N - c0; if (cvalid > 64) cvalid = 64;
    const short* vr = (const short*)vb;
    short8 afr[KK][4];
    load_afr<FP, KP, KK>(vr, c0, ln, quad, afr);
    for (int nt = wid; nt < NT; nt += 4) {
        int col = nt * 16 + ln;
        float bcol = (col < F) ? b[col] : 0.f;
        short8 bfr[KK];
        const short8* bp = (const short8*)(Wb + (size_t)col * KP + quad * 8);
        #pragma unroll
        for (int kk = 0; kk < KK; ++kk) bfr[kk] = bp[kk * 4];
        #pragma unroll
        for (int ms = 0; ms < 4; ++ms) {
            if (ms * 16 < cvalid) {
                floatx4 acc = {0.f, 0.f, 0.f, 0.f};
                #pragma unroll
                for (int kk = 0; kk < KK; ++kk)
                    acc = __builtin_amdgcn_mfma_f32_16x16x32_bf16(
                              afr[kk][ms], bfr[kk], acc, 0, 0, 0);
                #pragma unroll
                for (int r = 0; r < 4; ++r) {
                    int row = ms * 16 + quad * 4 + r;
                    if (row < cvalid) {
                        unsigned short hv = 0;
                        if (col < F) hv = (unsigned short)f2bf(fmaxf(acc[r] + bcol, 0.f));
                        h1b[(size_t)(c0 + row) * FP + col] = hv;
                    }
                }
            }
        }
    }
}

__global__ __launch_bounds__(256) void gin_linear_both_kernel(
        const unsigned short* vb1, const short* Wbl1, const float* bb1,
        unsigned short* h1b1, int N1, int nblk1,
        const unsigned short* vb2, const short* Wbl2, const float* bb2,
        unsigned short* h1b2, int N2) {
    int bid = blockIdx.x;
    if (bid < nblk1)
        gin_linear_dev<93, 96, 6, 96>(vb1, Wbl1, bb1, h1b1, N1, bid);
    else
        gin_linear_dev<43, 64, 3, 48>(vb2, Wbl2, bb2, h1b2, N2, bid - nblk1);
}

// ---- fused GIN layer 2 + pool MFMA, A-frags direct from global vb ---------
template<int F, int KP, int FO, int NT, int NS, int FP>
__device__ __forceinline__ void gin_pool_dev(
        const unsigned short* __restrict__ vb, const short* __restrict__ Wb,
        const float* __restrict__ b, const int* __restrict__ offs,
        float* __restrict__ ppmax, float* __restrict__ ppsum,
        int blk, float* pmaxL, float* psumL) {
    constexpr int KK = KP / 32;
    int g = blk / NS;
    int s = blk % NS;
    int tid = threadIdx.x;
    int wid = tid >> 6;
    int lane = tid & 63;
    int ln = lane & 15;
    int quad = lane >> 4;

    int gs0 = offs[g], ge0 = offs[g + 1];
    int per = (ge0 - gs0 + NS - 1) / NS;
    int gs = gs0 + s * per;
    int ge = gs + per; if (ge > ge0) ge = ge0;

    for (int i = tid; i < NT * 16; i += 256) { pmaxL[i] = 0.f; psumL[i] = 0.f; }
    __syncthreads();

    const short* vr = (const short*)vb;
    for (int c0 = gs; c0 < ge; c0 += 64) {
        int cvalid = ge - c0; if (cvalid > 64) cvalid = 64;
        short8 afr[KK][4];
        load_afr<FP, KP, KK>(vr, c0, ln, quad, afr);
        for (int nt = wid; nt < NT; nt += 4) {
            int col = nt * 16 + ln;
            float bcol = (col < FO) ? b[col] : 0.f;
            short8 bfr[KK];
            const short8* bp = (const short8*)(Wb + (size_t)col * KP + quad * 8);
            #pragma unroll
            for (int kk = 0; kk < KK; ++kk) bfr[kk] = bp[kk * 4];
            float cmx = 0.f, csm = 0.f;
            #pragma unroll
            for (int ms = 0; ms < 4; ++ms) {
                if (ms * 16 < cvalid) {
                    floatx4 acc = {0.f, 0.f, 0.f, 0.f};
                    #pragma unroll
                    for (int kk = 0; kk < KK; ++kk)
                        acc = __builtin_amdgcn_mfma_f32_16x16x32_bf16(
                                  afr[kk][ms], bfr[kk], acc, 0, 0, 0);
                    #pragma unroll
                    for (int r = 0; r < 4; ++r) {
                        int rowl = ms * 16 + quad * 4 + r;
                        float v = fmaxf(acc[r] + bcol, 0.f);
                        if (rowl < cvalid) { cmx = fmaxf(cmx, v); csm += v; }
                    }
                }
            }
            cmx = fmaxf(cmx, __shfl_xor(cmx, 16, 64));
            cmx = fmaxf(cmx, __shfl_xor(cmx, 32, 64));
            csm += __shfl_xor(csm, 16, 64);
            csm += __shfl_xor(csm, 32, 64);
            if (quad == 0) {                     // exclusive nt per wave
                int i = nt * 16 + ln;
                pmaxL[i] = fmaxf(pmaxL[i], cmx);
                psumL[i] += csm;
            }
        }
    }
    __syncthreads();
    float* om = ppmax + (size_t)(g * NS + s) * FO;
    float* os = ppsum + (size_t)(g * NS + s) * FO;
    for (int col = tid; col < FO; col += 256) { om[col] = pmaxL[col]; os[col] = psumL[col]; }
}

__global__ __launch_bounds__(256) void gin_pool_both_kernel(
        const unsigned short* vb1, const short* Wbg1, const float* b21,
        const int* offs1, float* pm1, float* ps1, int nblk1,
        const unsigned short* vb2, const short* Wbg2, const float* b22,
        const int* offs2, float* pm2, float* ps2) {
    __shared__ float pmaxL[944];
    __shared__ float psumL[944];
    int bid = blockIdx.x;
    if (bid < nblk1)
        gin_pool_dev<93, 96, 930, 59, 4, 96>(vb1, Wbg1, b21, offs1,
                                             pm1, ps1, bid, pmaxL, psumL);
    else
        gin_pool_dev<43, 64, 430, 27, 4, 48>(vb2, Wbg2, b22, offs2,
                                             pm2, ps2, bid - nblk1, pmaxL, psumL);
}

// ---- combine partial pools -> pb bf16 [NG][KPAD] --------------------------
template<int FO, int NS, int KPAD>
__device__ __forceinline__ void pool_reduce_dev(
        const float* __restrict__ ppmax, const float* __restrict__ ppsum,
        const int* __restrict__ offs, short* __restrict__ pb, int g) {
    int cntg = offs[g + 1] - offs[g];
    float den = (float)(cntg > 0 ? cntg : 1);
    for (int col = threadIdx.x; col < KPAD; col += 256) {
        float v = 0.f;
        if (col < FO) {
            float m = 0.f;
            #pragma unroll
            for (int ss = 0; ss < NS; ++ss)
                m = fmaxf(m, ppmax[(size_t)(g * NS + ss) * FO + col]);
            v = m;
        } else if (col < 2 * FO) {
            float sm = 0.f;
            #pragma unroll
            for (int ss = 0; ss < NS; ++ss)
                sm += ppsum[(size_t)(g * NS + ss) * FO + (col - FO)];
            v = sm / den;
        }
        pb[(size_t)g * KPAD + col] = f2bf(v);
    }
}

__global__ __launch_bounds__(256) void pool_reduce_both_kernel(
        const float* pm1, const float* ps1, const int* offs1, short* pb1,
        const float* pm2, const float* ps2, const int* offs2, short* pb2) {
    int bid = blockIdx.x;
    if (bid < NG) pool_reduce_dev<930, 4, 2048>(pm1, ps1, offs1, pb1, bid);
    else          pool_reduce_dev<430, 4, 1024>(pm2, ps2, offs2, pb2, bid - NG);
}

// ---- bf16 MFMA GEMM device body, split-K ----------------------------------
template<int KPC>
__device__ __forceinline__ void fc_mfma_dev(
        const short* __restrict__ Ab, const short* __restrict__ Wb,
        float* __restrict__ partial, int KP, int NB, int bid) {
    int mb = bid & 3;
    int nb = (bid >> 2) % NB;
    int ks = (bid >> 2) / NB;
    int tid = threadIdx.x;
    int w = tid >> 6;
    int lane = tid & 63;
    int ln = lane & 15, quad = lane >> 4;
    int row = mb * 64 + w * 16 + ln;
    const short* ap = Ab + (size_t)row * KP + ks * KPC + quad * 8;
    const short* wp = Wb + (size_t)(nb * 64 + ln) * KP + ks * KPC + quad * 8;
    floatx4 acc[4];
    #pragma unroll
    for (int ns = 0; ns < 4; ++ns) acc[ns] = {0.f, 0.f, 0.f, 0.f};
    #pragma unroll
    for (int kk = 0; kk < KPC / 32; ++kk) {
        short8 a = *(const short8*)(ap + kk * 32);
        #pragma unroll
        for (int ns = 0; ns < 4; ++ns) {
            short8 b = *(const short8*)(wp + (size_t)ns * 16 * KP + kk * 32);
            acc[ns] = __builtin_amdgcn_mfma_f32_16x16x32_bf16(a, b, acc[ns], 0, 0, 0);
        }
    }
    int N = NB * 64;
    float* pp = partial + ((size_t)ks * 256 + mb * 64 + w * 16) * N + nb * 64;
    #pragma unroll
    for (int ns = 0; ns < 4; ++ns)
        #pragma unroll
        for (int r = 0; r < 4; ++r)
            pp[(quad * 4 + r) * N + ns * 16 + ln] = acc[ns][r];
}

template<int KPC1, int KPC2>
__global__ __launch_bounds__(256) void fc_mfma_both_kernel(
        const short* A1, const short* B1, float* P1, int KPa, int NBa, int nblk1,
        const short* A2, const short* B2, float* P2, int KPb, int NBb) {
    int bid = blockIdx.x;
    if (bid < nblk1) fc_mfma_dev<KPC1>(A1, B1, P1, KPa, NBa, bid);
    else             fc_mfma_dev<KPC2>(A2, B2, P2, KPb, NBb, bid - nblk1);
}

// ---- split-K reduce (both branches) ---------------------------------------
template<int KS, bool RELU, bool WBF16, bool WF32>
__global__ __launch_bounds__(256) void fc_reduce_both_kernel(
        const float* __restrict__ P1, const float* __restrict__ b1v,
        short* __restrict__ ob1, float* __restrict__ of1, int MN1, int Nn1,
        const float* __restrict__ P2, const float* __restrict__ b2v,
        short* __restrict__ ob2, float* __restrict__ of2, int MN2, int Nn2) {
    int idx = blockIdx.x * 256 + threadIdx.x;
    const float* P; const float* bias; short* ob; float* of; int MN, Nn;
    if (idx < MN1) { P = P1; bias = b1v; ob = ob1; of = of1; MN = MN1; Nn = Nn1; }
    else {
        idx -= MN1;
        if (idx >= MN2) return;
        P = P2; bias = b2v; ob = ob2; of = of2; MN = MN2; Nn = Nn2;
    }
    float v = bias[idx % Nn];
    #pragma unroll
    for (int s = 0; s < KS; ++s) v += P[(size_t)s * MN + idx];
    if (RELU) v = fmaxf(v, 0.f);
    if (WBF16) ob[idx] = f2bf(v);
    if (WF32)  of[idx] = v;
}

// ---- fused head tail (both) -----------------------------------------------
template<int KS>
__global__ __launch_bounds__(256) void head_final_both_kernel(
        const float* __restrict__ P1, const float* __restrict__ b11,
        const float* __restrict__ w21, const float* __restrict__ b21,
        float* __restrict__ z1o,
        const float* __restrict__ P2, const float* __restrict__ b12,
        const float* __restrict__ w22, const float* __restrict__ b22,
        float* __restrict__ z2o) {
    int br = blockIdx.x >> 8;
    int row = blockIdx.x & 255;
    const float* P  = br ? P2  : P1;
    const float* b1 = br ? b12 : b11;
    const float* w2 = br ? w22 : w21;
    const float* b2 = br ? b22 : b21;
    float* zo       = br ? z2o : z1o;
    int t = threadIdx.x;
    float v = b1[t];
    int idx = row * 256 + t;
    #pragma unroll
    for (int s = 0; s < KS; ++s) v += P[(size_t)s * 65536 + idx];
    v = fmaxf(v, 0.f) * w2[t];
    #pragma unroll
    for (int o = 32; o > 0; o >>= 1) v += __shfl_down(v, o, 64);
    __shared__ float red[4];
    if ((t & 63) == 0) red[t >> 6] = v;
    __syncthreads();
    if (t == 0) zo[row] = red[0] + red[1] + red[2] + red[3] + b2[0];
}

// ---------------------------------------------------------------------------
extern "C" void kernel_launch(void* const* d_in, const int* in_sizes, int n_in,
                              void* d_out, int out_size, void* d_ws, size_t ws_size,
                              hipStream_t stream) {
    (void)n_in; (void)out_size; (void)ws_size;
    const float* x      = (const float*)d_in[1];
    const int*   ei     = (const int*)  d_in[2];
    const int*   batch  = (const int*)  d_in[3];
    const float* a      = (const float*)d_in[4];
    const int*   ed     = (const int*)  d_in[5];
    const int*   c      = (const int*)  d_in[6];
    const float* W1  = (const float*)d_in[7],  *b1  = (const float*)d_in[8];
    const float* W2  = (const float*)d_in[9],  *b2  = (const float*)d_in[10];
    const float* W3  = (const float*)d_in[11], *b3  = (const float*)d_in[12];
    const float* W4  = (const float*)d_in[13], *b4  = (const float*)d_in[14];
    const float* fg_w1  = (const float*)d_in[15], *fg_b1  = (const float*)d_in[16];
    const float* fg_w2  = (const float*)d_in[17], *fg_b2  = (const float*)d_in[18];
    const float* fg1_w1 = (const float*)d_in[19], *fg1_b1 = (const float*)d_in[20];
    const float* fg1_w2 = (const float*)d_in[21], *fg1_b2 = (const float*)d_in[22];
    const float* ff_w1  = (const float*)d_in[23], *ff_b1  = (const float*)d_in[24];
    const float* ff_w2  = (const float*)d_in[25], *ff_b2  = (const float*)d_in[26];
    const float* ff1_w1 = (const float*)d_in[27], *ff1_b1 = (const float*)d_in[28];
    const float* ff1_w2 = (const float*)d_in[29], *ff1_b2 = (const float*)d_in[30];

    const int N1 = in_sizes[1] / 93;
    const int E1 = in_sizes[2] / 2;
    const int N2 = in_sizes[4] / 43;
    const int E2 = in_sizes[5] / 2;

    float* out = (float*)d_out;
    float* z   = out;
    float* xg  = out + 256;
    float* xg1 = out + 256 + 256 * 512;
    float* z1  = out + 256 + 2 * 256 * 512;

    char* wsb = (char*)d_ws;
    size_t off = 0;
    auto carve = [&](size_t bytes) {
        void* ptr = wsb + off;
        off = (off + bytes + 255) & ~(size_t)255;
        return ptr;
    };
    unsigned short* xb1  = (unsigned short*)carve((size_t)N1 * 96 * 2);  // also pm1/ps1
    unsigned short* xb2  = (unsigned short*)carve((size_t)N2 * 48 * 2);  // also pm2/ps2
    unsigned short* vb1  = (unsigned short*)carve((size_t)(N1 + 64) * 96 * 2);
    unsigned short* vb2  = (unsigned short*)carve((size_t)(N2 + 64) * 48 * 2);
    unsigned short* h1b1 = (unsigned short*)carve((size_t)N1 * 96 * 2);
    unsigned short* h1b2 = (unsigned short*)carve((size_t)N2 * 48 * 2);
    short* pb1  = (short*)carve((size_t)NG * 2048 * 2);
    short* pb2  = (short*)carve((size_t)NG * 1024 * 2);
    short* t1b1 = (short*)carve((size_t)NG * 1024 * 2);
    short* t1b2 = (short*)carve((size_t)NG * 1024 * 2);
    short* xgb1 = (short*)carve((size_t)NG * 512 * 2);
    short* xgb2 = (short*)carve((size_t)NG * 512 * 2);
    float* partial1 = (float*)carve((size_t)8 * 256 * 1024 * 4);
    float* partial2 = (float*)carve((size_t)8 * 256 * 1024 * 4);
    short* Wbl1 = (short*)carve((size_t)96 * 96 * 2);
    short* Wbg1 = (short*)carve((size_t)944 * 96 * 2);
    short* Wbl2 = (short*)carve((size_t)48 * 64 * 2);
    short* Wbg2 = (short*)carve((size_t)432 * 64 * 2);
    short* Wb1a = (short*)carve((size_t)1024 * 2048 * 2);
    short* Wb2a = (short*)carve((size_t)512 * 1024 * 2);
    short* Wb3a = (short*)carve((size_t)256 * 512 * 2);
    short* Wb1b = (short*)carve((size_t)1024 * 1024 * 2);
    short* Wb2b = (short*)carve((size_t)512 * 1024 * 2);
    short* Wb3b = (short*)carve((size_t)256 * 512 * 2);
    int* offs1 = (int*)carve(257 * 4);
    int* offs2 = (int*)carve(257 * 4);
    int* deg   = (int*)carve((size_t)(N1 + N2) * 4);
    int* rowoff1 = (int*)carve((size_t)(N1 + 1) * 4);
    int* rowoff2 = (int*)carve((size_t)(N2 + 1) * 4);
    int* cursor1 = (int*)carve((size_t)N1 * 4);
    int* cursor2 = (int*)carve((size_t)N2 * 4);
    int* csr1  = (int*)carve((size_t)E1 * 4);
    int* csr2  = (int*)carve((size_t)E2 * 4);
    int* bsum  = (int*)carve(256 * 4);
    int* deg1 = deg, *deg2 = deg + N1;
    int* bsum1 = bsum, *bsum2 = bsum + 128;
    float* pm1 = (float*)xb1;                    // xb dead after gather1
    float* ps1 = pm1 + (size_t)NG * 4 * 930;
    float* pm2 = (float*)xb2;
    float* ps2 = pm2 + (size_t)NG * 4 * 430;

    constexpr int KS = 8;

    // ---- prologue: repacks, casts, offsets, windowed CSR build -----------
    RJobs10 jobs = {{
        { W1,     Wbl1, 93,   93,   96,   96   },
        { W2,     Wbg1, 93,   930,  944,  96   },
        { W3,     Wbl2, 43,   43,   48,   64   },
        { W4,     Wbg2, 43,   430,  432,  64   },
        { fg_w1,  Wb1a, 1860, 1024, 1024, 2048 },
        { fg_w2,  Wb2a, 1024, 512,  512,  1024 },
        { ff_w1,  Wb3a, 512,  256,  256,  512  },
        { fg1_w1, Wb1b, 860,  1024, 1024, 1024 },
        { fg1_w2, Wb2b, 1024, 512,  512,  1024 },
        { ff1_w1, Wb3b, 512,  256,  256,  512  },
    }};
    repack_all_kernel<<<dim3(512, 10), 256, 0, stream>>>(jobs);
    cast_both_kernel<<<cdiv(N1 * 96 + N2 * 48, 256), 256, 0, stream>>>(
        x, xb1, N1, a, xb2, N2);
    offs_both_kernel<<<4, 256, 0, stream>>>(batch, N1, offs1, c, N2, offs2);
    hipMemsetAsync(deg, 0, (size_t)(N1 + N2) * 4, stream);
    int nwb1 = cdiv(E1, CHK) * 8, nwb2 = cdiv(E2, CHK) * 8;
    deg_win_both_kernel<<<nwb1 + nwb2, 256, 0, stream>>>(ei, E1, N1, deg1, nwb1,
                                                         ed, E2, N2, deg2);
    int nb1 = cdiv(N1, 1024), nb2 = cdiv(N2, 1024);
    scan1_both_kernel<<<nb1 + nb2, 256, 0, stream>>>(deg1, N1, rowoff1, bsum1, nb1,
                                                     deg2, N2, rowoff2, bsum2);
    scan2_both_kernel<<<2, 64, 0, stream>>>(bsum1, nb1, bsum2, nb2);
    int nc1 = cdiv(N1, 256), nc2 = cdiv(N2, 256);
    scan3_both_kernel<<<nc1 + nc2, 256, 0, stream>>>(rowoff1, bsum1, cursor1, N1, E1,
                                                     rowoff2, bsum2, cursor2, N2, E2, nc1);
    fill_win_both_kernel<<<nwb1 + nwb2, 256, 0, stream>>>(ei, E1, N1, cursor1, csr1, nwb1,
                                                          ed, E2, N2, cursor2, csr2);

    // ---- merged GIN chains (vb = self + neighbor sum, bf16 rows) ---------
    int ng1 = cdiv(N1, 4), ng2 = cdiv(N2, 4);
    gather_both_kernel<<<ng1 + ng2, 256, 0, stream>>>(
        xb1, csr1, rowoff1, vb1, N1, ng1, xb2, csr2, rowoff2, vb2, N2);
    int nl1 = cdiv(N1, 64), nl2 = cdiv(N2, 64);
    gin_linear_both_kernel<<<nl1 + nl2, 256, 0, stream>>>(
        vb1, Wbl1, b1, h1b1, N1, nl1, vb2, Wbl2, b3, h1b2, N2);
    gather_both_kernel<<<ng1 + ng2, 256, 0, stream>>>(
        h1b1, csr1, rowoff1, vb1, N1, ng1, h1b2, csr2, rowoff2, vb2, N2);
    gin_pool_both_kernel<<<NG * 4 * 2, 256, 0, stream>>>(
        vb1, Wbg1, b2, offs1, pm1, ps1, NG * 4,
        vb2, Wbg2, b4, offs2, pm2, ps2);
    pool_reduce_both_kernel<<<2 * NG, 256, 0, stream>>>(
        pm1, ps1, offs1, pb1, pm2, ps2, offs2, pb2);

    // ---- merged FC stack -------------------------------------------------
    fc_mfma_both_kernel<256, 128><<<1024, 256, 0, stream>>>(
        pb1, Wb1a, partial1, 2048, 16, 512, pb2, Wb1b, partial2, 1024, 16);
    fc_reduce_both_kernel<KS, true, true, false><<<cdiv(2 * 256 * 1024, 256), 256, 0, stream>>>(
        partial1, fg_b1, t1b1, nullptr, 256 * 1024, 1024,
        partial2, fg1_b1, t1b2, nullptr, 256 * 1024, 1024);
    fc_mfma_both_kernel<128, 128><<<512, 256, 0, stream>>>(
        t1b1, Wb2a, partial1, 1024, 8, 256, t1b2, Wb2b, partial2, 1024, 8);
    fc_reduce_both_kernel<KS, false, true, true><<<cdiv(2 * 256 * 512, 256), 256, 0, stream>>>(
        partial1, fg_b2, xgb1, xg, 256 * 512, 512,
        partial2, fg1_b2, xgb2, xg1, 256 * 512, 512);
    fc_mfma_both_kernel<64, 64><<<256, 256, 0, stream>>>(
        xgb1, Wb3a, partial1, 512, 4, 128, xgb2, Wb3b, partial2, 512, 4);
    head_final_both_kernel<KS><<<512, 256, 0, stream>>>(
        partial1, ff_b1, ff_w2, ff_b2, z,
        partial2, ff1_b1, ff1_w2, ff1_b2, z1);
}

// Round 12
// 453.182 us; speedup vs baseline: 1.0021x; 1.0021x over previous
//
#include <hip/hip_runtime.h>

// ---------------------------------------------------------------------------
// Round 12: gather tail removal via clamped-index branchless unroll (R11 tail
// serialized ~half the edges); branch-2 rows padded to 128B cachelines
// (FP=64 == KP, 1 line/edge vs 1.5); cast+memset+offs fused into one
// prologue kernel. Everything else unchanged from R11.
// ---------------------------------------------------------------------------

static constexpr int NG  = 256;   // graphs
static constexpr int CHK = 4096;  // edges per (chunk,window) block

typedef short  short8  __attribute__((ext_vector_type(8)));
typedef float  floatx4 __attribute__((ext_vector_type(4)));

__device__ __forceinline__ short f2bf(float f) {
    unsigned u = __float_as_uint(f);
    u += 0x7fff + ((u >> 16) & 1);          // RNE to bf16
    return (short)(u >> 16);
}
__device__ __forceinline__ float bf_lo(unsigned u) { return __uint_as_float(u << 16); }
__device__ __forceinline__ float bf_hi(unsigned u) { return __uint_as_float(u & 0xffff0000u); }

static inline int cdiv(int a, int b) { return (a + b - 1) / b; }

// ---- fused prologue: casts (bf16 padded rows), deg zeroing, offs bsearch --
__global__ __launch_bounds__(256) void prologue_kernel(
        const float* __restrict__ x1, unsigned short* __restrict__ xb1, int N1,
        const float* __restrict__ x2, unsigned short* __restrict__ xb2, int N2,
        const int* __restrict__ seg1, int* __restrict__ offs1,
        const int* __restrict__ seg2, int* __restrict__ offs2,
        int* __restrict__ deg, int castB1, int castB2, int degB) {
    int b = blockIdx.x;
    int t = threadIdx.x;
    if (b < castB1) {
        int idx = b * 256 + t;
        if (idx < N1 * 96) {
            int n = idx / 96, k = idx - n * 96;
            xb1[idx] = (unsigned short)f2bf(k < 93 ? x1[(size_t)n * 93 + k] : 0.f);
        }
    } else if (b < castB1 + castB2) {
        int idx = (b - castB1) * 256 + t;
        if (idx < N2 * 64) {
            int n = idx >> 6, k = idx & 63;
            xb2[idx] = (unsigned short)f2bf(k < 43 ? x2[(size_t)n * 43 + k] : 0.f);
        }
    } else if (b < castB1 + castB2 + degB) {
        int idx = (b - castB1 - castB2) * 256 + t;
        if (idx < N1 + N2) deg[idx] = 0;
    } else {
        int br = b - castB1 - castB2 - degB;   // 0 or 1
        const int* seg = br ? seg2 : seg1;
        int N = br ? N2 : N1;
        int* offs = br ? offs2 : offs1;
        for (int g = t; g <= NG; g += 256) {
            int lo = 0, hi = N;
            while (lo < hi) {
                int mid = (lo + hi) >> 1;
                if (seg[mid] < g) lo = mid + 1; else hi = mid;
            }
            offs[g] = lo;
        }
    }
}

// ---- windowed degree histogram (XCD-affine: window = bid & 7) -------------
__device__ __forceinline__ void deg_win_dev(const int* __restrict__ ei, int E, int N,
                                            int* __restrict__ deg, int bid) {
    int win = bid & 7, chunk = bid >> 3;
    int e0 = chunk * CHK;
    int e1 = e0 + CHK; if (e1 > E) e1 = E;
    int wlo = (int)((long)win * N / 8);
    int whi = (int)((long)(win + 1) * N / 8);
    for (int e = e0 + threadIdx.x; e < e1; e += 256) {
        int dst = ei[E + e];
        if (dst >= wlo && dst < whi) atomicAdd(&deg[dst], 1);
    }
}

__global__ __launch_bounds__(256) void deg_win_both_kernel(
        const int* ei1, int E1, int N1, int* d1, int nblk1,
        const int* ei2, int E2, int N2, int* d2) {
    int bid = blockIdx.x;
    if (bid < nblk1) deg_win_dev(ei1, E1, N1, d1, bid);
    else             deg_win_dev(ei2, E2, N2, d2, bid - nblk1);
}

// ---- prefix scans ---------------------------------------------------------
__global__ __launch_bounds__(256) void scan1_both_kernel(
        const int* __restrict__ d1, int N1, int* __restrict__ x1, int* __restrict__ bs1, int nb1,
        const int* __restrict__ d2, int N2, int* __restrict__ x2, int* __restrict__ bs2) {
    __shared__ int sh[256];
    const int* deg; int* excl; int* bsum; int N; int blk;
    if ((int)blockIdx.x < nb1) { deg = d1; excl = x1; bsum = bs1; N = N1; blk = blockIdx.x; }
    else { deg = d2; excl = x2; bsum = bs2; N = N2; blk = blockIdx.x - nb1; }
    int base = blk * 1024;
    int t = threadIdx.x;
    int v[4];
    int s = 0;
    #pragma unroll
    for (int i = 0; i < 4; ++i) {
        int idx = base + t * 4 + i;
        v[i] = s;
        s += (idx < N) ? deg[idx] : 0;
    }
    sh[t] = s;
    __syncthreads();
    for (int off = 1; off < 256; off <<= 1) {
        int xv = (t >= off) ? sh[t - off] : 0;
        __syncthreads();
        sh[t] += xv;
        __syncthreads();
    }
    int texcl = (t > 0) ? sh[t - 1] : 0;
    #pragma unroll
    for (int i = 0; i < 4; ++i) {
        int idx = base + t * 4 + i;
        if (idx < N) excl[idx] = texcl + v[i];
    }
    if (t == 255) bsum[blk] = sh[255];
}

__global__ void scan2_both_kernel(int* __restrict__ b1, int nb1,
                                  int* __restrict__ b2, int nb2) {
    if (threadIdx.x) return;
    int* b = blockIdx.x ? b2 : b1;
    int nb = blockIdx.x ? nb2 : nb1;
    int acc = 0;
    for (int i = 0; i < nb; ++i) { int t = b[i]; b[i] = acc; acc += t; }
}

__global__ void scan3_both_kernel(int* __restrict__ x1, const int* __restrict__ bs1,
                                  int* __restrict__ c1, int N1, int Ev1,
                                  int* __restrict__ x2, const int* __restrict__ bs2,
                                  int* __restrict__ c2, int N2, int Ev2, int nc1) {
    int bid = blockIdx.x;
    int* excl; const int* bsum; int* cur; int N, E, i;
    if (bid < nc1) { i = bid * 256 + threadIdx.x; excl = x1; bsum = bs1; cur = c1; N = N1; E = Ev1; }
    else { i = (bid - nc1) * 256 + threadIdx.x; excl = x2; bsum = bs2; cur = c2; N = N2; E = Ev2; }
    if (i < N) {
        int v = excl[i] + bsum[i >> 10];
        excl[i] = v;
        cur[i] = v;
    }
    if (i == 0) excl[N] = E;
}

// ---- windowed CSR fill (XCD-affine) ---------------------------------------
__device__ __forceinline__ void fill_win_dev(const int* __restrict__ ei, int E, int N,
                                             int* __restrict__ cursor, int* __restrict__ csr,
                                             int bid) {
    int win = bid & 7, chunk = bid >> 3;
    int e0 = chunk * CHK;
    int e1 = e0 + CHK; if (e1 > E) e1 = E;
    int wlo = (int)((long)win * N / 8);
    int whi = (int)((long)(win + 1) * N / 8);
    for (int e = e0 + threadIdx.x; e < e1; e += 256) {
        int dst = ei[E + e];
        if (dst >= wlo && dst < whi) {
            int pos = atomicAdd(&cursor[dst], 1);
            csr[pos] = ei[e];
        }
    }
}

__global__ __launch_bounds__(256) void fill_win_both_kernel(
        const int* ei1, int E1, int N1, int* c1, int* s1, int nblk1,
        const int* ei2, int E2, int N2, int* c2, int* s2) {
    int bid = blockIdx.x;
    if (bid < nblk1) fill_win_dev(ei1, E1, N1, c1, s1, bid);
    else             fill_win_dev(ei2, E2, N2, c2, s2, bid - nblk1);
}

// ---- unified weight repack via LDS transpose tile -------------------------
struct RJob { const float* W; short* Wb; int K, Nsrc, Ndst, KP; };
struct RJobs10 { RJob j[10]; };

__global__ __launch_bounds__(256) void repack_all_kernel(RJobs10 jobs) {
    __shared__ __align__(16) short sh[64][72];
    RJob jb = jobs.j[blockIdx.y];
    int tilesC = (jb.Ndst + 63) >> 6;
    int tilesK = (jb.KP + 63) >> 6;
    if ((int)blockIdx.x >= tilesC * tilesK) return;
    int c0 = ((int)blockIdx.x % tilesC) * 64;
    int k0 = ((int)blockIdx.x / tilesC) * 64;
    int t = threadIdx.x;
    #pragma unroll 4
    for (int idx = t; idx < 64 * 64; idx += 256) {
        int kk = idx >> 6, cc = idx & 63;
        int k = k0 + kk, cg = c0 + cc;
        float v = (k < jb.K && cg < jb.Nsrc) ? jb.W[(size_t)k * jb.Nsrc + cg] : 0.f;
        sh[cc][kk] = f2bf(v);
    }
    __syncthreads();
    int kt = jb.KP - k0; if (kt > 64) kt = 64;
    int chunks = kt >> 3;
    for (int idx = t; idx < 64 * chunks; idx += 256) {
        int cc = idx / chunks, ch = idx - cc * chunks;
        int cg = c0 + cc;
        if (cg < jb.Ndst) {
            uint4 v = *(const uint4*)&sh[cc][ch * 8];
            *(uint4*)&jb.Wb[(size_t)cg * jb.KP + k0 + ch * 8] = v;
        }
    }
}

// ---- gather + GIN self-add: vb[n] = bf16(src[n] + sum_{e: dst==n} src[e]) -
// Clamped-index branchless unroll: full ILP depth every iteration, no tail.
// GROUPS=1: 8 loads in flight; GROUPS=2: 2 lane-groups x 4, shfl combine.
template<int FP, int GROUPS>
__device__ __forceinline__ void gather_dev(
        const unsigned short* __restrict__ src, const int* __restrict__ csr,
        const int* __restrict__ ro, unsigned short* __restrict__ vb, int N, int bid) {
    int wave = (bid * 256 + threadIdx.x) >> 6;
    int lane = threadIdx.x & 63;
    if (wave >= N) return;
    constexpr int HW = FP / 2;
    const unsigned* base = (const unsigned*)src;
    unsigned* out = (unsigned*)vb;
    int s = ro[wave], e = ro[wave + 1];
    int grp, l;
    if (GROUPS == 2) { grp = lane >> 5; l = lane & 31; }
    else             { grp = 0;         l = lane;      }
    bool act = l < HW;
    unsigned su = (act && grp == 0) ? base[(size_t)wave * HW + l] : 0u;
    float lo = bf_lo(su), hi = bf_hi(su);        // self term (GIN eps=0)
    if (GROUPS == 1) {
        for (int i = s; i < e; i += 8) {
            unsigned u[8];
            #pragma unroll
            for (int q = 0; q < 8; ++q) {
                int j = i + q;
                int jj = j < e ? j : e - 1;          // clamp (dup row = line hit)
                u[q] = act ? base[(size_t)csr[jj] * HW + l] : 0u;
            }
            #pragma unroll
            for (int q = 0; q < 8; ++q)
                if (i + q < e) { lo += bf_lo(u[q]); hi += bf_hi(u[q]); }
        }
    } else {
        for (int i = s + grp; i < e; i += 8) {       // group edges: i,i+2,i+4,i+6
            unsigned u[4];
            #pragma unroll
            for (int q = 0; q < 4; ++q) {
                int j = i + 2 * q;
                int jj = j < e ? j : e - 1;
                u[q] = act ? base[(size_t)csr[jj] * HW + l] : 0u;
            }
            #pragma unroll
            for (int q = 0; q < 4; ++q)
                if (i + 2 * q < e) { lo += bf_lo(u[q]); hi += bf_hi(u[q]); }
        }
        lo += __shfl_xor(lo, 32, 64);
        hi += __shfl_xor(hi, 32, 64);
    }
    if (grp == 0 && act) {
        unsigned plo = (unsigned)(unsigned short)f2bf(lo);
        unsigned phi = (unsigned)(unsigned short)f2bf(hi);
        out[(size_t)wave * HW + l] = (phi << 16) | plo;
    }
}

__global__ __launch_bounds__(256) void gather_both_kernel(
        const unsigned short* s1, const int* csr1, const int* ro1,
        unsigned short* vb1, int N1, int nblk1,
        const unsigned short* s2, const int* csr2, const int* ro2,
        unsigned short* vb2, int N2) {
    int bid = blockIdx.x;
    if (bid < nblk1) gather_dev<96, 1>(s1, csr1, ro1, vb1, N1, bid);
    else             gather_dev<64, 2>(s2, csr2, ro2, vb2, N2, bid - nblk1);
}

// ---- A-frag loader from global vb rows (FP == KP for both branches now) ---
template<int FP, int KP, int KK>
__device__ __forceinline__ void load_afr(const short* __restrict__ vr,
                                         int row0, int ln, int quad,
                                         short8 afr[][4]) {
    #pragma unroll
    for (int ms = 0; ms < 4; ++ms) {
        const short* rp = vr + (size_t)(row0 + ms * 16 + ln) * FP;
        #pragma unroll
        for (int kk = 0; kk < KK; ++kk) {
            int offk = kk * 32 + quad * 8;
            short8 v = {0, 0, 0, 0, 0, 0, 0, 0};
            if (FP == KP || offk + 8 <= FP)
                v = *(const short8*)(rp + offk);
            afr[kk][ms] = v;
        }
    }
}

// ---- GIN layer 1 MFMA, A-frags direct from global vb ----------------------
template<int F, int KP, int NT, int FP>
__device__ __forceinline__ void gin_linear_dev(
        const unsigned short* __restrict__ vb, const short* __restrict__ Wb,
        const float* __restrict__ b, unsigned short* __restrict__ h1b,
        int N, int blk) {
    constexpr int KK = KP / 32;
    int c0 = blk * 64;
    int tid = threadIdx.x;
    int wid = tid >> 6;
    int lane = tid & 63;
    int ln = lane & 15, quad = lane >> 4;
    int cvalid = N - c0; if (cvalid > 64) cvalid = 64;
    const short* vr = (const short*)vb;
    short8 afr[KK][4];
    load_afr<FP, KP, KK>(vr, c0, ln, quad, afr);
    for (int nt = wid; nt < NT; nt += 4) {
        int col = nt * 16 + ln;
        float bcol = (col < F) ? b[col] : 0.f;
        short8 bfr[KK];
        const short8* bp = (const short8*)(Wb + (size_t)col * KP + quad * 8);
        #pragma unroll
        for (int kk = 0; kk < KK; ++kk) bfr[kk] = bp[kk * 4];
        #pragma unroll
        for (int ms = 0; ms < 4; ++ms) {
            if (ms * 16 < cvalid) {
                floatx4 acc = {0.f, 0.f, 0.f, 0.f};
                #pragma unroll
                for (int kk = 0; kk < KK; ++kk)
                    acc = __builtin_amdgcn_mfma_f32_16x16x32_bf16(
                              afr[kk][ms], bfr[kk], acc, 0, 0, 0);
                #pragma unroll
                for (int r = 0; r < 4; ++r) {
                    int row = ms * 16 + quad * 4 + r;
                    if (row < cvalid) {
                        unsigned short hv = 0;
                        if (col < F) hv = (unsigned short)f2bf(fmaxf(acc[r] + bcol, 0.f));
                        if (col < FP)
                            h1b[(size_t)(c0 + row) * FP + col] = hv;
                    }
                }
            }
        }
    }
}

__global__ __launch_bounds__(256) void gin_linear_both_kernel(
        const unsigned short* vb1, const short* Wbl1, const float* bb1,
        unsigned short* h1b1, int N1, int nblk1,
        const unsigned short* vb2, const short* Wbl2, const float* bb2,
        unsigned short* h1b2, int N2) {
    int bid = blockIdx.x;
    if (bid < nblk1)
        gin_linear_dev<93, 96, 6, 96>(vb1, Wbl1, bb1, h1b1, N1, bid);
    else
        gin_linear_dev<43, 64, 4, 64>(vb2, Wbl2, bb2, h1b2, N2, bid - nblk1);
}

// ---- fused GIN layer 2 + pool MFMA, A-frags direct from global vb ---------
template<int F, int KP, int FO, int NT, int NS, int FP>
__device__ __forceinline__ void gin_pool_dev(
        const unsigned short* __restrict__ vb, const short* __restrict__ Wb,
        const float* __restrict__ b, const int* __restrict__ offs,
        float* __restrict__ ppmax, float* __restrict__ ppsum,
        int blk, float* pmaxL, float* psumL) {
    constexpr int KK = KP / 32;
    int g = blk / NS;
    int s = blk % NS;
    int tid = threadIdx.x;
    int wid = tid >> 6;
    int lane = tid & 63;
    int ln = lane & 15;
    int quad = lane >> 4;

    int gs0 = offs[g], ge0 = offs[g + 1];
    int per = (ge0 - gs0 + NS - 1) / NS;
    int gs = gs0 + s * per;
    int ge = gs + per; if (ge > ge0) ge = ge0;

    for (int i = tid; i < NT * 16; i += 256) { pmaxL[i] = 0.f; psumL[i] = 0.f; }
    __syncthreads();

    const short* vr = (const short*)vb;
    for (int c0 = gs; c0 < ge; c0 += 64) {
        int cvalid = ge - c0; if (cvalid > 64) cvalid = 64;
        short8 afr[KK][4];
        load_afr<FP, KP, KK>(vr, c0, ln, quad, afr);
        for (int nt = wid; nt < NT; nt += 4) {
            int col = nt * 16 + ln;
            float bcol = (col < FO) ? b[col] : 0.f;
            short8 bfr[KK];
            const short8* bp = (const short8*)(Wb + (size_t)col * KP + quad * 8);
            #pragma unroll
            for (int kk = 0; kk < KK; ++kk) bfr[kk] = bp[kk * 4];
            float cmx = 0.f, csm = 0.f;
            #pragma unroll
            for (int ms = 0; ms < 4; ++ms) {
                if (ms * 16 < cvalid) {
                    floatx4 acc = {0.f, 0.f, 0.f, 0.f};
                    #pragma unroll
                    for (int kk = 0; kk < KK; ++kk)
                        acc = __builtin_amdgcn_mfma_f32_16x16x32_bf16(
                                  afr[kk][ms], bfr[kk], acc, 0, 0, 0);
                    #pragma unroll
                    for (int r = 0; r < 4; ++r) {
                        int rowl = ms * 16 + quad * 4 + r;
                        float v = fmaxf(acc[r] + bcol, 0.f);
                        if (rowl < cvalid) { cmx = fmaxf(cmx, v); csm += v; }
                    }
                }
            }
            cmx = fmaxf(cmx, __shfl_xor(cmx, 16, 64));
            cmx = fmaxf(cmx, __shfl_xor(cmx, 32, 64));
            csm += __shfl_xor(csm, 16, 64);
            csm += __shfl_xor(csm, 32, 64);
            if (quad == 0) {                     // exclusive nt per wave
                int i = nt * 16 + ln;
                pmaxL[i] = fmaxf(pmaxL[i], cmx);
                psumL[i] += csm;
            }
        }
    }
    __syncthreads();
    float* om = ppmax + (size_t)(g * NS + s) * FO;
    float* os = ppsum + (size_t)(g * NS + s) * FO;
    for (int col = tid; col < FO; col += 256) { om[col] = pmaxL[col]; os[col] = psumL[col]; }
}

__global__ __launch_bounds__(256) void gin_pool_both_kernel(
        const unsigned short* vb1, const short* Wbg1, const float* b21,
        const int* offs1, float* pm1, float* ps1, int nblk1,
        const unsigned short* vb2, const short* Wbg2, const float* b22,
        const int* offs2, float* pm2, float* ps2) {
    __shared__ float pmaxL[944];
    __shared__ float psumL[944];
    int bid = blockIdx.x;
    if (bid < nblk1)
        gin_pool_dev<93, 96, 930, 59, 4, 96>(vb1, Wbg1, b21, offs1,
                                             pm1, ps1, bid, pmaxL, psumL);
    else
        gin_pool_dev<43, 64, 430, 27, 4, 64>(vb2, Wbg2, b22, offs2,
                                             pm2, ps2, bid - nblk1, pmaxL, psumL);
}

// ---- combine partial pools -> pb bf16 [NG][KPAD] --------------------------
template<int FO, int NS, int KPAD>
__device__ __forceinline__ void pool_reduce_dev(
        const float* __restrict__ ppmax, const float* __restrict__ ppsum,
        const int* __restrict__ offs, short* __restrict__ pb, int g) {
    int cntg = offs[g + 1] - offs[g];
    float den = (float)(cntg > 0 ? cntg : 1);
    for (int col = threadIdx.x; col < KPAD; col += 256) {
        float v = 0.f;
        if (col < FO) {
            float m = 0.f;
            #pragma unroll
            for (int ss = 0; ss < NS; ++ss)
                m = fmaxf(m, ppmax[(size_t)(g * NS + ss) * FO + col]);
            v = m;
        } else if (col < 2 * FO) {
            float sm = 0.f;
            #pragma unroll
            for (int ss = 0; ss < NS; ++ss)
                sm += ppsum[(size_t)(g * NS + ss) * FO + (col - FO)];
            v = sm / den;
        }
        pb[(size_t)g * KPAD + col] = f2bf(v);
    }
}

__global__ __launch_bounds__(256) void pool_reduce_both_kernel(
        const float* pm1, const float* ps1, const int* offs1, short* pb1,
        const float* pm2, const float* ps2, const int* offs2, short* pb2) {
    int bid = blockIdx.x;
    if (bid < NG) pool_reduce_dev<930, 4, 2048>(pm1, ps1, offs1, pb1, bid);
    else          pool_reduce_dev<430, 4, 1024>(pm2, ps2, offs2, pb2, bid - NG);
}

// ---- bf16 MFMA GEMM device body, split-K ----------------------------------
template<int KPC>
__device__ __forceinline__ void fc_mfma_dev(
        const short* __restrict__ Ab, const short* __restrict__ Wb,
        float* __restrict__ partial, int KP, int NB, int bid) {
    int mb = bid & 3;
    int nb = (bid >> 2) % NB;
    int ks = (bid >> 2) / NB;
    int tid = threadIdx.x;
    int w = tid >> 6;
    int lane = tid & 63;
    int ln = lane & 15, quad = lane >> 4;
    int row = mb * 64 + w * 16 + ln;
    const short* ap = Ab + (size_t)row * KP + ks * KPC + quad * 8;
    const short* wp = Wb + (size_t)(nb * 64 + ln) * KP + ks * KPC + quad * 8;
    floatx4 acc[4];
    #pragma unroll
    for (int ns = 0; ns < 4; ++ns) acc[ns] = {0.f, 0.f, 0.f, 0.f};
    #pragma unroll
    for (int kk = 0; kk < KPC / 32; ++kk) {
        short8 a = *(const short8*)(ap + kk * 32);
        #pragma unroll
        for (int ns = 0; ns < 4; ++ns) {
            short8 b = *(const short8*)(wp + (size_t)ns * 16 * KP + kk * 32);
            acc[ns] = __builtin_amdgcn_mfma_f32_16x16x32_bf16(a, b, acc[ns], 0, 0, 0);
        }
    }
    int N = NB * 64;
    float* pp = partial + ((size_t)ks * 256 + mb * 64 + w * 16) * N + nb * 64;
    #pragma unroll
    for (int ns = 0; ns < 4; ++ns)
        #pragma unroll
        for (int r = 0; r < 4; ++r)
            pp[(quad * 4 + r) * N + ns * 16 + ln] = acc[ns][r];
}

template<int KPC1, int KPC2>
__global__ __launch_bounds__(256) void fc_mfma_both_kernel(
        const short* A1, const short* B1, float* P1, int KPa, int NBa, int nblk1,
        const short* A2, const short* B2, float* P2, int KPb, int NBb) {
    int bid = blockIdx.x;
    if (bid < nblk1) fc_mfma_dev<KPC1>(A1, B1, P1, KPa, NBa, bid);
    else             fc_mfma_dev<KPC2>(A2, B2, P2, KPb, NBb, bid - nblk1);
}

// ---- split-K reduce (both branches) ---------------------------------------
template<int KS, bool RELU, bool WBF16, bool WF32>
__global__ __launch_bounds__(256) void fc_reduce_both_kernel(
        const float* __restrict__ P1, const float* __restrict__ b1v,
        short* __restrict__ ob1, float* __restrict__ of1, int MN1, int Nn1,
        const float* __restrict__ P2, const float* __restrict__ b2v,
        short* __restrict__ ob2, float* __restrict__ of2, int MN2, int Nn2) {
    int idx = blockIdx.x * 256 + threadIdx.x;
    const float* P; const float* bias; short* ob; float* of; int MN, Nn;
    if (idx < MN1) { P = P1; bias = b1v; ob = ob1; of = of1; MN = MN1; Nn = Nn1; }
    else {
        idx -= MN1;
        if (idx >= MN2) return;
        P = P2; bias = b2v; ob = ob2; of = of2; MN = MN2; Nn = Nn2;
    }
    float v = bias[idx % Nn];
    #pragma unroll
    for (int s = 0; s < KS; ++s) v += P[(size_t)s * MN + idx];
    if (RELU) v = fmaxf(v, 0.f);
    if (WBF16) ob[idx] = f2bf(v);
    if (WF32)  of[idx] = v;
}

// ---- fused head tail (both) -----------------------------------------------
template<int KS>
__global__ __launch_bounds__(256) void head_final_both_kernel(
        const float* __restrict__ P1, const float* __restrict__ b11,
        const float* __restrict__ w21, const float* __restrict__ b21,
        float* __restrict__ z1o,
        const float* __restrict__ P2, const float* __restrict__ b12,
        const float* __restrict__ w22, const float* __restrict__ b22,
        float* __restrict__ z2o) {
    int br = blockIdx.x >> 8;
    int row = blockIdx.x & 255;
    const float* P  = br ? P2  : P1;
    const float* b1 = br ? b12 : b11;
    const float* w2 = br ? w22 : w21;
    const float* b2 = br ? b22 : b21;
    float* zo       = br ? z2o : z1o;
    int t = threadIdx.x;
    float v = b1[t];
    int idx = row * 256 + t;
    #pragma unroll
    for (int s = 0; s < KS; ++s) v += P[(size_t)s * 65536 + idx];
    v = fmaxf(v, 0.f) * w2[t];
    #pragma unroll
    for (int o = 32; o > 0; o >>= 1) v += __shfl_down(v, o, 64);
    __shared__ float red[4];
    if ((t & 63) == 0) red[t >> 6] = v;
    __syncthreads();
    if (t == 0) zo[row] = red[0] + red[1] + red[2] + red[3] + b2[0];
}

// ---------------------------------------------------------------------------
extern "C" void kernel_launch(void* const* d_in, const int* in_sizes, int n_in,
                              void* d_out, int out_size, void* d_ws, size_t ws_size,
                              hipStream_t stream) {
    (void)n_in; (void)out_size; (void)ws_size;
    const float* x      = (const float*)d_in[1];
    const int*   ei     = (const int*)  d_in[2];
    const int*   batch  = (const int*)  d_in[3];
    const float* a      = (const float*)d_in[4];
    const int*   ed     = (const int*)  d_in[5];
    const int*   c      = (const int*)  d_in[6];
    const float* W1  = (const float*)d_in[7],  *b1  = (const float*)d_in[8];
    const float* W2  = (const float*)d_in[9],  *b2  = (const float*)d_in[10];
    const float* W3  = (const float*)d_in[11], *b3  = (const float*)d_in[12];
    const float* W4  = (const float*)d_in[13], *b4  = (const float*)d_in[14];
    const float* fg_w1  = (const float*)d_in[15], *fg_b1  = (const float*)d_in[16];
    const float* fg_w2  = (const float*)d_in[17], *fg_b2  = (const float*)d_in[18];
    const float* fg1_w1 = (const float*)d_in[19], *fg1_b1 = (const float*)d_in[20];
    const float* fg1_w2 = (const float*)d_in[21], *fg1_b2 = (const float*)d_in[22];
    const float* ff_w1  = (const float*)d_in[23], *ff_b1  = (const float*)d_in[24];
    const float* ff_w2  = (const float*)d_in[25], *ff_b2  = (const float*)d_in[26];
    const float* ff1_w1 = (const float*)d_in[27], *ff1_b1 = (const float*)d_in[28];
    const float* ff1_w2 = (const float*)d_in[29], *ff1_b2 = (const float*)d_in[30];

    const int N1 = in_sizes[1] / 93;
    const int E1 = in_sizes[2] / 2;
    const int N2 = in_sizes[4] / 43;
    const int E2 = in_sizes[5] / 2;

    float* out = (float*)d_out;
    float* z   = out;
    float* xg  = out + 256;
    float* xg1 = out + 256 + 256 * 512;
    float* z1  = out + 256 + 2 * 256 * 512;

    char* wsb = (char*)d_ws;
    size_t off = 0;
    auto carve = [&](size_t bytes) {
        void* ptr = wsb + off;
        off = (off + bytes + 255) & ~(size_t)255;
        return ptr;
    };
    unsigned short* xb1  = (unsigned short*)carve((size_t)N1 * 96 * 2);  // also pm1/ps1
    unsigned short* xb2  = (unsigned short*)carve((size_t)N2 * 64 * 2);  // also pm2/ps2
    unsigned short* vb1  = (unsigned short*)carve((size_t)(N1 + 64) * 96 * 2);
    unsigned short* vb2  = (unsigned short*)carve((size_t)(N2 + 64) * 64 * 2);
    unsigned short* h1b1 = (unsigned short*)carve((size_t)N1 * 96 * 2);
    unsigned short* h1b2 = (unsigned short*)carve((size_t)N2 * 64 * 2);
    short* pb1  = (short*)carve((size_t)NG * 2048 * 2);
    short* pb2  = (short*)carve((size_t)NG * 1024 * 2);
    short* t1b1 = (short*)carve((size_t)NG * 1024 * 2);
    short* t1b2 = (short*)carve((size_t)NG * 1024 * 2);
    short* xgb1 = (short*)carve((size_t)NG * 512 * 2);
    short* xgb2 = (short*)carve((size_t)NG * 512 * 2);
    float* partial1 = (float*)carve((size_t)8 * 256 * 1024 * 4);
    float* partial2 = (float*)carve((size_t)8 * 256 * 1024 * 4);
    short* Wbl1 = (short*)carve((size_t)96 * 96 * 2);
    short* Wbg1 = (short*)carve((size_t)944 * 96 * 2);
    short* Wbl2 = (short*)carve((size_t)64 * 64 * 2);
    short* Wbg2 = (short*)carve((size_t)432 * 64 * 2);
    short* Wb1a = (short*)carve((size_t)1024 * 2048 * 2);
    short* Wb2a = (short*)carve((size_t)512 * 1024 * 2);
    short* Wb3a = (short*)carve((size_t)256 * 512 * 2);
    short* Wb1b = (short*)carve((size_t)1024 * 1024 * 2);
    short* Wb2b = (short*)carve((size_t)512 * 1024 * 2);
    short* Wb3b = (short*)carve((size_t)256 * 512 * 2);
    int* offs1 = (int*)carve(257 * 4);
    int* offs2 = (int*)carve(257 * 4);
    int* deg   = (int*)carve((size_t)(N1 + N2) * 4);
    int* rowoff1 = (int*)carve((size_t)(N1 + 1) * 4);
    int* rowoff2 = (int*)carve((size_t)(N2 + 1) * 4);
    int* cursor1 = (int*)carve((size_t)N1 * 4);
    int* cursor2 = (int*)carve((size_t)N2 * 4);
    int* csr1  = (int*)carve((size_t)E1 * 4);
    int* csr2  = (int*)carve((size_t)E2 * 4);
    int* bsum  = (int*)carve(256 * 4);
    int* deg1 = deg, *deg2 = deg + N1;
    int* bsum1 = bsum, *bsum2 = bsum + 128;
    float* pm1 = (float*)xb1;                    // xb dead after gather1
    float* ps1 = pm1 + (size_t)NG * 4 * 930;
    float* pm2 = (float*)xb2;
    float* ps2 = pm2 + (size_t)NG * 4 * 430;

    constexpr int KS = 8;

    // ---- prologue: repacks + fused cast/deg-zero/offs + windowed CSR -----
    RJobs10 jobs = {{
        { W1,     Wbl1, 93,   93,   96,   96   },
        { W2,     Wbg1, 93,   930,  944,  96   },
        { W3,     Wbl2, 43,   43,   64,   64   },
        { W4,     Wbg2, 43,   430,  432,  64   },
        { fg_w1,  Wb1a, 1860, 1024, 1024, 2048 },
        { fg_w2,  Wb2a, 1024, 512,  512,  1024 },
        { ff_w1,  Wb3a, 512,  256,  256,  512  },
        { fg1_w1, Wb1b, 860,  1024, 1024, 1024 },
        { fg1_w2, Wb2b, 1024, 512,  512,  1024 },
        { ff1_w1, Wb3b, 512,  256,  256,  512  },
    }};
    repack_all_kernel<<<dim3(512, 10), 256, 0, stream>>>(jobs);
    int castB1 = cdiv(N1 * 96, 256), castB2 = cdiv(N2 * 64, 256);
    int degB = cdiv(N1 + N2, 256);
    prologue_kernel<<<castB1 + castB2 + degB + 2, 256, 0, stream>>>(
        x, xb1, N1, a, xb2, N2, batch, offs1, c, offs2, deg, castB1, castB2, degB);
    int nwb1 = cdiv(E1, CHK) * 8, nwb2 = cdiv(E2, CHK) * 8;
    deg_win_both_kernel<<<nwb1 + nwb2, 256, 0, stream>>>(ei, E1, N1, deg1, nwb1,
                                                         ed, E2, N2, deg2);
    int nb1 = cdiv(N1, 1024), nb2 = cdiv(N2, 1024);
    scan1_both_kernel<<<nb1 + nb2, 256, 0, stream>>>(deg1, N1, rowoff1, bsum1, nb1,
                                                     deg2, N2, rowoff2, bsum2);
    scan2_both_kernel<<<2, 64, 0, stream>>>(bsum1, nb1, bsum2, nb2);
    int nc1 = cdiv(N1, 256), nc2 = cdiv(N2, 256);
    scan3_both_kernel<<<nc1 + nc2, 256, 0, stream>>>(rowoff1, bsum1, cursor1, N1, E1,
                                                     rowoff2, bsum2, cursor2, N2, E2, nc1);
    fill_win_both_kernel<<<nwb1 + nwb2, 256, 0, stream>>>(ei, E1, N1, cursor1, csr1, nwb1,
                                                          ed, E2, N2, cursor2, csr2);

    // ---- merged GIN chains (vb = self + neighbor sum, bf16 rows) ---------
    int ng1 = cdiv(N1, 4), ng2 = cdiv(N2, 4);
    gather_both_kernel<<<ng1 + ng2, 256, 0, stream>>>(
        xb1, csr1, rowoff1, vb1, N1, ng1, xb2, csr2, rowoff2, vb2, N2);
    int nl1 = cdiv(N1, 64), nl2 = cdiv(N2, 64);
    gin_linear_both_kernel<<<nl1 + nl2, 256, 0, stream>>>(
        vb1, Wbl1, b1, h1b1, N1, nl1, vb2, Wbl2, b3, h1b2, N2);
    gather_both_kernel<<<ng1 + ng2, 256, 0, stream>>>(
        h1b1, csr1, rowoff1, vb1, N1, ng1, h1b2, csr2, rowoff2, vb2, N2);
    gin_pool_both_kernel<<<NG * 4 * 2, 256, 0, stream>>>(
        vb1, Wbg1, b2, offs1, pm1, ps1, NG * 4,
        vb2, Wbg2, b4, offs2, pm2, ps2);
    pool_reduce_both_kernel<<<2 * NG, 256, 0, stream>>>(
        pm1, ps1, offs1, pb1, pm2, ps2, offs2, pb2);

    // ---- merged FC stack -------------------------------------------------
    fc_mfma_both_kernel<256, 128><<<1024, 256, 0, stream>>>(
        pb1, Wb1a, partial1, 2048, 16, 512, pb2, Wb1b, partial2, 1024, 16);
    fc_reduce_both_kernel<KS, true, true, false><<<cdiv(2 * 256 * 1024, 256), 256, 0, stream>>>(
        partial1, fg_b1, t1b1, nullptr, 256 * 1024, 1024,
        partial2, fg1_b1, t1b2, nullptr, 256 * 1024, 1024);
    fc_mfma_both_kernel<128, 128><<<512, 256, 0, stream>>>(
        t1b1, Wb2a, partial1, 1024, 8, 256, t1b2, Wb2b, partial2, 1024, 8);
    fc_reduce_both_kernel<KS, false, true, true><<<cdiv(2 * 256 * 512, 256), 256, 0, stream>>>(
        partial1, fg_b2, xgb1, xg, 256 * 512, 512,
        partial2, fg1_b2, xgb2, xg1, 256 * 512, 512);
    fc_mfma_both_kernel<64, 64><<<256, 256, 0, stream>>>(
        xgb1, Wb3a, partial1, 512, 4, 128, xgb2, Wb3b, partial2, 512, 4);
    head_final_both_kernel<KS><<<512, 256, 0, stream>>>(
        partial1, ff_b1, ff_w2, ff_b2, z,
        partial2, ff1_b1, ff1_w2, ff1_b2, z1);
}

// Round 13
// 448.226 us; speedup vs baseline: 1.0132x; 1.0111x over previous
//
#include <hip/hip_runtime.h>

// ---------------------------------------------------------------------------
// Round 13: middle-tier consolidation -- KS 8->4 (fc partial traffic halves),
// NS 4->2 (pool partials + weight cold-reads halve), scan2 folded into scan3.
// Gathers confirmed at structural floor (compulsory L2-fill, no per-XCD reuse
// possible: deg~8 edges/row spread over 8 XCDs); left as R12.
// ---------------------------------------------------------------------------

static constexpr int NG  = 256;   // graphs
static constexpr int CHK = 4096;  // edges per (chunk,window) block

typedef short  short8  __attribute__((ext_vector_type(8)));
typedef float  floatx4 __attribute__((ext_vector_type(4)));

__device__ __forceinline__ short f2bf(float f) {
    unsigned u = __float_as_uint(f);
    u += 0x7fff + ((u >> 16) & 1);          // RNE to bf16
    return (short)(u >> 16);
}
__device__ __forceinline__ float bf_lo(unsigned u) { return __uint_as_float(u << 16); }
__device__ __forceinline__ float bf_hi(unsigned u) { return __uint_as_float(u & 0xffff0000u); }

static inline int cdiv(int a, int b) { return (a + b - 1) / b; }

// ---- fused prologue: casts (bf16 padded rows), deg zeroing, offs bsearch --
__global__ __launch_bounds__(256) void prologue_kernel(
        const float* __restrict__ x1, unsigned short* __restrict__ xb1, int N1,
        const float* __restrict__ x2, unsigned short* __restrict__ xb2, int N2,
        const int* __restrict__ seg1, int* __restrict__ offs1,
        const int* __restrict__ seg2, int* __restrict__ offs2,
        int* __restrict__ deg, int castB1, int castB2, int degB) {
    int b = blockIdx.x;
    int t = threadIdx.x;
    if (b < castB1) {
        int idx = b * 256 + t;
        if (idx < N1 * 96) {
            int n = idx / 96, k = idx - n * 96;
            xb1[idx] = (unsigned short)f2bf(k < 93 ? x1[(size_t)n * 93 + k] : 0.f);
        }
    } else if (b < castB1 + castB2) {
        int idx = (b - castB1) * 256 + t;
        if (idx < N2 * 64) {
            int n = idx >> 6, k = idx & 63;
            xb2[idx] = (unsigned short)f2bf(k < 43 ? x2[(size_t)n * 43 + k] : 0.f);
        }
    } else if (b < castB1 + castB2 + degB) {
        int idx = (b - castB1 - castB2) * 256 + t;
        if (idx < N1 + N2) deg[idx] = 0;
    } else {
        int br = b - castB1 - castB2 - degB;   // 0 or 1
        const int* seg = br ? seg2 : seg1;
        int N = br ? N2 : N1;
        int* offs = br ? offs2 : offs1;
        for (int g = t; g <= NG; g += 256) {
            int lo = 0, hi = N;
            while (lo < hi) {
                int mid = (lo + hi) >> 1;
                if (seg[mid] < g) lo = mid + 1; else hi = mid;
            }
            offs[g] = lo;
        }
    }
}

// ---- windowed degree histogram (XCD-affine: window = bid & 7) -------------
__device__ __forceinline__ void deg_win_dev(const int* __restrict__ ei, int E, int N,
                                            int* __restrict__ deg, int bid) {
    int win = bid & 7, chunk = bid >> 3;
    int e0 = chunk * CHK;
    int e1 = e0 + CHK; if (e1 > E) e1 = E;
    int wlo = (int)((long)win * N / 8);
    int whi = (int)((long)(win + 1) * N / 8);
    for (int e = e0 + threadIdx.x; e < e1; e += 256) {
        int dst = ei[E + e];
        if (dst >= wlo && dst < whi) atomicAdd(&deg[dst], 1);
    }
}

__global__ __launch_bounds__(256) void deg_win_both_kernel(
        const int* ei1, int E1, int N1, int* d1, int nblk1,
        const int* ei2, int E2, int N2, int* d2) {
    int bid = blockIdx.x;
    if (bid < nblk1) deg_win_dev(ei1, E1, N1, d1, bid);
    else             deg_win_dev(ei2, E2, N2, d2, bid - nblk1);
}

// ---- prefix scans ---------------------------------------------------------
__global__ __launch_bounds__(256) void scan1_both_kernel(
        const int* __restrict__ d1, int N1, int* __restrict__ x1, int* __restrict__ bs1, int nb1,
        const int* __restrict__ d2, int N2, int* __restrict__ x2, int* __restrict__ bs2) {
    __shared__ int sh[256];
    const int* deg; int* excl; int* bsum; int N; int blk;
    if ((int)blockIdx.x < nb1) { deg = d1; excl = x1; bsum = bs1; N = N1; blk = blockIdx.x; }
    else { deg = d2; excl = x2; bsum = bs2; N = N2; blk = blockIdx.x - nb1; }
    int base = blk * 1024;
    int t = threadIdx.x;
    int v[4];
    int s = 0;
    #pragma unroll
    for (int i = 0; i < 4; ++i) {
        int idx = base + t * 4 + i;
        v[i] = s;
        s += (idx < N) ? deg[idx] : 0;
    }
    sh[t] = s;
    __syncthreads();
    for (int off = 1; off < 256; off <<= 1) {
        int xv = (t >= off) ? sh[t - off] : 0;
        __syncthreads();
        sh[t] += xv;
        __syncthreads();
    }
    int texcl = (t > 0) ? sh[t - 1] : 0;
    #pragma unroll
    for (int i = 0; i < 4; ++i) {
        int idx = base + t * 4 + i;
        if (idx < N) excl[idx] = texcl + v[i];
    }
    if (t == 255) bsum[blk] = sh[255];
}

// scan3 with inline bsum prefix (absorbs old scan2) + cursor write
__global__ void scan3_both_kernel(int* __restrict__ x1, const int* __restrict__ bs1,
                                  int* __restrict__ c1, int N1, int Ev1, int nb1,
                                  int* __restrict__ x2, const int* __restrict__ bs2,
                                  int* __restrict__ c2, int N2, int Ev2, int nc1) {
    int bid = blockIdx.x;
    int* excl; const int* bsum; int* cur; int N, E, i;
    if (bid < nc1) { i = bid * 256 + threadIdx.x; excl = x1; bsum = bs1; cur = c1; N = N1; E = Ev1; }
    else { i = (bid - nc1) * 256 + threadIdx.x; excl = x2; bsum = bs2; cur = c2; N = N2; E = Ev2; }
    (void)nb1;
    if (i < N) {
        int blk = i >> 10;                    // scan1 block containing i
        int offp = 0;
        for (int j = 0; j < blk; ++j) offp += bsum[j];   // uniform scalar loop
        int v = excl[i] + offp;
        excl[i] = v;
        cur[i] = v;
    }
    if (i == 0) excl[N] = E;
}

// ---- windowed CSR fill (XCD-affine) ---------------------------------------
__device__ __forceinline__ void fill_win_dev(const int* __restrict__ ei, int E, int N,
                                             int* __restrict__ cursor, int* __restrict__ csr,
                                             int bid) {
    int win = bid & 7, chunk = bid >> 3;
    int e0 = chunk * CHK;
    int e1 = e0 + CHK; if (e1 > E) e1 = E;
    int wlo = (int)((long)win * N / 8);
    int whi = (int)((long)(win + 1) * N / 8);
    for (int e = e0 + threadIdx.x; e < e1; e += 256) {
        int dst = ei[E + e];
        if (dst >= wlo && dst < whi) {
            int pos = atomicAdd(&cursor[dst], 1);
            csr[pos] = ei[e];
        }
    }
}

__global__ __launch_bounds__(256) void fill_win_both_kernel(
        const int* ei1, int E1, int N1, int* c1, int* s1, int nblk1,
        const int* ei2, int E2, int N2, int* c2, int* s2) {
    int bid = blockIdx.x;
    if (bid < nblk1) fill_win_dev(ei1, E1, N1, c1, s1, bid);
    else             fill_win_dev(ei2, E2, N2, c2, s2, bid - nblk1);
}

// ---- unified weight repack via LDS transpose tile -------------------------
struct RJob { const float* W; short* Wb; int K, Nsrc, Ndst, KP; };
struct RJobs10 { RJob j[10]; };

__global__ __launch_bounds__(256) void repack_all_kernel(RJobs10 jobs) {
    __shared__ __align__(16) short sh[64][72];
    RJob jb = jobs.j[blockIdx.y];
    int tilesC = (jb.Ndst + 63) >> 6;
    int tilesK = (jb.KP + 63) >> 6;
    if ((int)blockIdx.x >= tilesC * tilesK) return;
    int c0 = ((int)blockIdx.x % tilesC) * 64;
    int k0 = ((int)blockIdx.x / tilesC) * 64;
    int t = threadIdx.x;
    #pragma unroll 4
    for (int idx = t; idx < 64 * 64; idx += 256) {
        int kk = idx >> 6, cc = idx & 63;
        int k = k0 + kk, cg = c0 + cc;
        float v = (k < jb.K && cg < jb.Nsrc) ? jb.W[(size_t)k * jb.Nsrc + cg] : 0.f;
        sh[cc][kk] = f2bf(v);
    }
    __syncthreads();
    int kt = jb.KP - k0; if (kt > 64) kt = 64;
    int chunks = kt >> 3;
    for (int idx = t; idx < 64 * chunks; idx += 256) {
        int cc = idx / chunks, ch = idx - cc * chunks;
        int cg = c0 + cc;
        if (cg < jb.Ndst) {
            uint4 v = *(const uint4*)&sh[cc][ch * 8];
            *(uint4*)&jb.Wb[(size_t)cg * jb.KP + k0 + ch * 8] = v;
        }
    }
}

// ---- gather + GIN self-add: vb[n] = bf16(src[n] + sum_{e: dst==n} src[e]) -
template<int FP, int GROUPS>
__device__ __forceinline__ void gather_dev(
        const unsigned short* __restrict__ src, const int* __restrict__ csr,
        const int* __restrict__ ro, unsigned short* __restrict__ vb, int N, int bid) {
    int wave = (bid * 256 + threadIdx.x) >> 6;
    int lane = threadIdx.x & 63;
    if (wave >= N) return;
    constexpr int HW = FP / 2;
    const unsigned* base = (const unsigned*)src;
    unsigned* out = (unsigned*)vb;
    int s = ro[wave], e = ro[wave + 1];
    int grp, l;
    if (GROUPS == 2) { grp = lane >> 5; l = lane & 31; }
    else             { grp = 0;         l = lane;      }
    bool act = l < HW;
    unsigned su = (act && grp == 0) ? base[(size_t)wave * HW + l] : 0u;
    float lo = bf_lo(su), hi = bf_hi(su);        // self term (GIN eps=0)
    if (GROUPS == 1) {
        for (int i = s; i < e; i += 8) {
            unsigned u[8];
            #pragma unroll
            for (int q = 0; q < 8; ++q) {
                int j = i + q;
                int jj = j < e ? j : e - 1;          // clamp (dup row = line hit)
                u[q] = act ? base[(size_t)csr[jj] * HW + l] : 0u;
            }
            #pragma unroll
            for (int q = 0; q < 8; ++q)
                if (i + q < e) { lo += bf_lo(u[q]); hi += bf_hi(u[q]); }
        }
    } else {
        for (int i = s + grp; i < e; i += 8) {       // group edges: i,i+2,i+4,i+6
            unsigned u[4];
            #pragma unroll
            for (int q = 0; q < 4; ++q) {
                int j = i + 2 * q;
                int jj = j < e ? j : e - 1;
                u[q] = act ? base[(size_t)csr[jj] * HW + l] : 0u;
            }
            #pragma unroll
            for (int q = 0; q < 4; ++q)
                if (i + 2 * q < e) { lo += bf_lo(u[q]); hi += bf_hi(u[q]); }
        }
        lo += __shfl_xor(lo, 32, 64);
        hi += __shfl_xor(hi, 32, 64);
    }
    if (grp == 0 && act) {
        unsigned plo = (unsigned)(unsigned short)f2bf(lo);
        unsigned phi = (unsigned)(unsigned short)f2bf(hi);
        out[(size_t)wave * HW + l] = (phi << 16) | plo;
    }
}

__global__ __launch_bounds__(256) void gather_both_kernel(
        const unsigned short* s1, const int* csr1, const int* ro1,
        unsigned short* vb1, int N1, int nblk1,
        const unsigned short* s2, const int* csr2, const int* ro2,
        unsigned short* vb2, int N2) {
    int bid = blockIdx.x;
    if (bid < nblk1) gather_dev<96, 1>(s1, csr1, ro1, vb1, N1, bid);
    else             gather_dev<64, 2>(s2, csr2, ro2, vb2, N2, bid - nblk1);
}

// ---- A-frag loader from global vb rows (FP == KP for both branches) -------
template<int FP, int KP, int KK>
__device__ __forceinline__ void load_afr(const short* __restrict__ vr,
                                         int row0, int ln, int quad,
                                         short8 afr[][4]) {
    #pragma unroll
    for (int ms = 0; ms < 4; ++ms) {
        const short* rp = vr + (size_t)(row0 + ms * 16 + ln) * FP;
        #pragma unroll
        for (int kk = 0; kk < KK; ++kk) {
            int offk = kk * 32 + quad * 8;
            short8 v = {0, 0, 0, 0, 0, 0, 0, 0};
            if (FP == KP || offk + 8 <= FP)
                v = *(const short8*)(rp + offk);
            afr[kk][ms] = v;
        }
    }
}

// ---- GIN layer 1 MFMA, A-frags direct from global vb ----------------------
template<int F, int KP, int NT, int FP>
__device__ __forceinline__ void gin_linear_dev(
        const unsigned short* __restrict__ vb, const short* __restrict__ Wb,
        const float* __restrict__ b, unsigned short* __restrict__ h1b,
        int N, int blk) {
    constexpr int KK = KP / 32;
    int c0 = blk * 64;
    int tid = threadIdx.x;
    int wid = tid >> 6;
    int lane = tid & 63;
    int ln = lane & 15, quad = lane >> 4;
    int cvalid = N - c0; if (cvalid > 64) cvalid = 64;
    const short* vr = (const short*)vb;
    short8 afr[KK][4];
    load_afr<FP, KP, KK>(vr, c0, ln, quad, afr);
    for (int nt = wid; nt < NT; nt += 4) {
        int col = nt * 16 + ln;
        float bcol = (col < F) ? b[col] : 0.f;
        short8 bfr[KK];
        const short8* bp = (const short8*)(Wb + (size_t)col * KP + quad * 8);
        #pragma unroll
        for (int kk = 0; kk < KK; ++kk) bfr[kk] = bp[kk * 4];
        #pragma unroll
        for (int ms = 0; ms < 4; ++ms) {
            if (ms * 16 < cvalid) {
                floatx4 acc = {0.f, 0.f, 0.f, 0.f};
                #pragma unroll
                for (int kk = 0; kk < KK; ++kk)
                    acc = __builtin_amdgcn_mfma_f32_16x16x32_bf16(
                              afr[kk][ms], bfr[kk], acc, 0, 0, 0);
                #pragma unroll
                for (int r = 0; r < 4; ++r) {
                    int row = ms * 16 + quad * 4 + r;
                    if (row < cvalid) {
                        unsigned short hv = 0;
                        if (col < F) hv = (unsigned short)f2bf(fmaxf(acc[r] + bcol, 0.f));
                        if (col < FP)
                            h1b[(size_t)(c0 + row) * FP + col] = hv;
                    }
                }
            }
        }
    }
}

__global__ __launch_bounds__(256) void gin_linear_both_kernel(
        const unsigned short* vb1, const short* Wbl1, const float* bb1,
        unsigned short* h1b1, int N1, int nblk1,
        const unsigned short* vb2, const short* Wbl2, const float* bb2,
        unsigned short* h1b2, int N2) {
    int bid = blockIdx.x;
    if (bid < nblk1)
        gin_linear_dev<93, 96, 6, 96>(vb1, Wbl1, bb1, h1b1, N1, bid);
    else
        gin_linear_dev<43, 64, 4, 64>(vb2, Wbl2, bb2, h1b2, N2, bid - nblk1);
}

// ---- fused GIN layer 2 + pool MFMA, A-frags direct from global vb ---------
template<int F, int KP, int FO, int NT, int NS, int FP>
__device__ __forceinline__ void gin_pool_dev(
        const unsigned short* __restrict__ vb, const short* __restrict__ Wb,
        const float* __restrict__ b, const int* __restrict__ offs,
        float* __restrict__ ppmax, float* __restrict__ ppsum,
        int blk, float* pmaxL, float* psumL) {
    constexpr int KK = KP / 32;
    int g = blk / NS;
    int s = blk % NS;
    int tid = threadIdx.x;
    int wid = tid >> 6;
    int lane = tid & 63;
    int ln = lane & 15;
    int quad = lane >> 4;

    int gs0 = offs[g], ge0 = offs[g + 1];
    int per = (ge0 - gs0 + NS - 1) / NS;
    int gs = gs0 + s * per;
    int ge = gs + per; if (ge > ge0) ge = ge0;

    for (int i = tid; i < NT * 16; i += 256) { pmaxL[i] = 0.f; psumL[i] = 0.f; }
    __syncthreads();

    const short* vr = (const short*)vb;
    for (int c0 = gs; c0 < ge; c0 += 64) {
        int cvalid = ge - c0; if (cvalid > 64) cvalid = 64;
        short8 afr[KK][4];
        load_afr<FP, KP, KK>(vr, c0, ln, quad, afr);
        for (int nt = wid; nt < NT; nt += 4) {
            int col = nt * 16 + ln;
            float bcol = (col < FO) ? b[col] : 0.f;
            short8 bfr[KK];
            const short8* bp = (const short8*)(Wb + (size_t)col * KP + quad * 8);
            #pragma unroll
            for (int kk = 0; kk < KK; ++kk) bfr[kk] = bp[kk * 4];
            float cmx = 0.f, csm = 0.f;
            #pragma unroll
            for (int ms = 0; ms < 4; ++ms) {
                if (ms * 16 < cvalid) {
                    floatx4 acc = {0.f, 0.f, 0.f, 0.f};
                    #pragma unroll
                    for (int kk = 0; kk < KK; ++kk)
                        acc = __builtin_amdgcn_mfma_f32_16x16x32_bf16(
                                  afr[kk][ms], bfr[kk], acc, 0, 0, 0);
                    #pragma unroll
                    for (int r = 0; r < 4; ++r) {
                        int rowl = ms * 16 + quad * 4 + r;
                        float v = fmaxf(acc[r] + bcol, 0.f);
                        if (rowl < cvalid) { cmx = fmaxf(cmx, v); csm += v; }
                    }
                }
            }
            cmx = fmaxf(cmx, __shfl_xor(cmx, 16, 64));
            cmx = fmaxf(cmx, __shfl_xor(cmx, 32, 64));
            csm += __shfl_xor(csm, 16, 64);
            csm += __shfl_xor(csm, 32, 64);
            if (quad == 0) {                     // exclusive nt per wave
                int i = nt * 16 + ln;
                pmaxL[i] = fmaxf(pmaxL[i], cmx);
                psumL[i] += csm;
            }
        }
    }
    __syncthreads();
    float* om = ppmax + (size_t)(g * NS + s) * FO;
    float* os = ppsum + (size_t)(g * NS + s) * FO;
    for (int col = tid; col < FO; col += 256) { om[col] = pmaxL[col]; os[col] = psumL[col]; }
}

__global__ __launch_bounds__(256) void gin_pool_both_kernel(
        const unsigned short* vb1, const short* Wbg1, const float* b21,
        const int* offs1, float* pm1, float* ps1, int nblk1,
        const unsigned short* vb2, const short* Wbg2, const float* b22,
        const int* offs2, float* pm2, float* ps2) {
    __shared__ float pmaxL[944];
    __shared__ float psumL[944];
    int bid = blockIdx.x;
    if (bid < nblk1)
        gin_pool_dev<93, 96, 930, 59, 2, 96>(vb1, Wbg1, b21, offs1,
                                             pm1, ps1, bid, pmaxL, psumL);
    else
        gin_pool_dev<43, 64, 430, 27, 2, 64>(vb2, Wbg2, b22, offs2,
                                             pm2, ps2, bid - nblk1, pmaxL, psumL);
}

// ---- combine partial pools -> pb bf16 [NG][KPAD] --------------------------
template<int FO, int NS, int KPAD>
__device__ __forceinline__ void pool_reduce_dev(
        const float* __restrict__ ppmax, const float* __restrict__ ppsum,
        const int* __restrict__ offs, short* __restrict__ pb, int g) {
    int cntg = offs[g + 1] - offs[g];
    float den = (float)(cntg > 0 ? cntg : 1);
    for (int col = threadIdx.x; col < KPAD; col += 256) {
        float v = 0.f;
        if (col < FO) {
            float m = 0.f;
            #pragma unroll
            for (int ss = 0; ss < NS; ++ss)
                m = fmaxf(m, ppmax[(size_t)(g * NS + ss) * FO + col]);
            v = m;
        } else if (col < 2 * FO) {
            float sm = 0.f;
            #pragma unroll
            for (int ss = 0; ss < NS; ++ss)
                sm += ppsum[(size_t)(g * NS + ss) * FO + (col - FO)];
            v = sm / den;
        }
        pb[(size_t)g * KPAD + col] = f2bf(v);
    }
}

__global__ __launch_bounds__(256) void pool_reduce_both_kernel(
        const float* pm1, const float* ps1, const int* offs1, short* pb1,
        const float* pm2, const float* ps2, const int* offs2, short* pb2) {
    int bid = blockIdx.x;
    if (bid < NG) pool_reduce_dev<930, 2, 2048>(pm1, ps1, offs1, pb1, bid);
    else          pool_reduce_dev<430, 2, 1024>(pm2, ps2, offs2, pb2, bid - NG);
}

// ---- bf16 MFMA GEMM device body, split-K ----------------------------------
template<int KPC>
__device__ __forceinline__ void fc_mfma_dev(
        const short* __restrict__ Ab, const short* __restrict__ Wb,
        float* __restrict__ partial, int KP, int NB, int bid) {
    int mb = bid & 3;
    int nb = (bid >> 2) % NB;
    int ks = (bid >> 2) / NB;
    int tid = threadIdx.x;
    int w = tid >> 6;
    int lane = tid & 63;
    int ln = lane & 15, quad = lane >> 4;
    int row = mb * 64 + w * 16 + ln;
    const short* ap = Ab + (size_t)row * KP + ks * KPC + quad * 8;
    const short* wp = Wb + (size_t)(nb * 64 + ln) * KP + ks * KPC + quad * 8;
    floatx4 acc[4];
    #pragma unroll
    for (int ns = 0; ns < 4; ++ns) acc[ns] = {0.f, 0.f, 0.f, 0.f};
    #pragma unroll
    for (int kk = 0; kk < KPC / 32; ++kk) {
        short8 a = *(const short8*)(ap + kk * 32);
        #pragma unroll
        for (int ns = 0; ns < 4; ++ns) {
            short8 b = *(const short8*)(wp + (size_t)ns * 16 * KP + kk * 32);
            acc[ns] = __builtin_amdgcn_mfma_f32_16x16x32_bf16(a, b, acc[ns], 0, 0, 0);
        }
    }
    int N = NB * 64;
    float* pp = partial + ((size_t)ks * 256 + mb * 64 + w * 16) * N + nb * 64;
    #pragma unroll
    for (int ns = 0; ns < 4; ++ns)
        #pragma unroll
        for (int r = 0; r < 4; ++r)
            pp[(quad * 4 + r) * N + ns * 16 + ln] = acc[ns][r];
}

template<int KPC1, int KPC2>
__global__ __launch_bounds__(256) void fc_mfma_both_kernel(
        const short* A1, const short* B1, float* P1, int KPa, int NBa, int nblk1,
        const short* A2, const short* B2, float* P2, int KPb, int NBb) {
    int bid = blockIdx.x;
    if (bid < nblk1) fc_mfma_dev<KPC1>(A1, B1, P1, KPa, NBa, bid);
    else             fc_mfma_dev<KPC2>(A2, B2, P2, KPb, NBb, bid - nblk1);
}

// ---- split-K reduce (both branches) ---------------------------------------
template<int KS, bool RELU, bool WBF16, bool WF32>
__global__ __launch_bounds__(256) void fc_reduce_both_kernel(
        const float* __restrict__ P1, const float* __restrict__ b1v,
        short* __restrict__ ob1, float* __restrict__ of1, int MN1, int Nn1,
        const float* __restrict__ P2, const float* __restrict__ b2v,
        short* __restrict__ ob2, float* __restrict__ of2, int MN2, int Nn2) {
    int idx = blockIdx.x * 256 + threadIdx.x;
    const float* P; const float* bias; short* ob; float* of; int MN, Nn;
    if (idx < MN1) { P = P1; bias = b1v; ob = ob1; of = of1; MN = MN1; Nn = Nn1; }
    else {
        idx -= MN1;
        if (idx >= MN2) return;
        P = P2; bias = b2v; ob = ob2; of = of2; MN = MN2; Nn = Nn2;
    }
    float v = bias[idx % Nn];
    #pragma unroll
    for (int s = 0; s < KS; ++s) v += P[(size_t)s * MN + idx];
    if (RELU) v = fmaxf(v, 0.f);
    if (WBF16) ob[idx] = f2bf(v);
    if (WF32)  of[idx] = v;
}

// ---- fused head tail (both) -----------------------------------------------
template<int KS>
__global__ __launch_bounds__(256) void head_final_both_kernel(
        const float* __restrict__ P1, const float* __restrict__ b11,
        const float* __restrict__ w21, const float* __restrict__ b21,
        float* __restrict__ z1o,
        const float* __restrict__ P2, const float* __restrict__ b12,
        const float* __restrict__ w22, const float* __restrict__ b22,
        float* __restrict__ z2o) {
    int br = blockIdx.x >> 8;
    int row = blockIdx.x & 255;
    const float* P  = br ? P2  : P1;
    const float* b1 = br ? b12 : b11;
    const float* w2 = br ? w22 : w21;
    const float* b2 = br ? b22 : b21;
    float* zo       = br ? z2o : z1o;
    int t = threadIdx.x;
    float v = b1[t];
    int idx = row * 256 + t;
    #pragma unroll
    for (int s = 0; s < KS; ++s) v += P[(size_t)s * 65536 + idx];
    v = fmaxf(v, 0.f) * w2[t];
    #pragma unroll
    for (int o = 32; o > 0; o >>= 1) v += __shfl_down(v, o, 64);
    __shared__ float red[4];
    if ((t & 63) == 0) red[t >> 6] = v;
    __syncthreads();
    if (t == 0) zo[row] = red[0] + red[1] + red[2] + red[3] + b2[0];
}

// ---------------------------------------------------------------------------
extern "C" void kernel_launch(void* const* d_in, const int* in_sizes, int n_in,
                              void* d_out, int out_size, void* d_ws, size_t ws_size,
                              hipStream_t stream) {
    (void)n_in; (void)out_size; (void)ws_size;
    const float* x      = (const float*)d_in[1];
    const int*   ei     = (const int*)  d_in[2];
    const int*   batch  = (const int*)  d_in[3];
    const float* a      = (const float*)d_in[4];
    const int*   ed     = (const int*)  d_in[5];
    const int*   c      = (const int*)  d_in[6];
    const float* W1  = (const float*)d_in[7],  *b1  = (const float*)d_in[8];
    const float* W2  = (const float*)d_in[9],  *b2  = (const float*)d_in[10];
    const float* W3  = (const float*)d_in[11], *b3  = (const float*)d_in[12];
    const float* W4  = (const float*)d_in[13], *b4  = (const float*)d_in[14];
    const float* fg_w1  = (const float*)d_in[15], *fg_b1  = (const float*)d_in[16];
    const float* fg_w2  = (const float*)d_in[17], *fg_b2  = (const float*)d_in[18];
    const float* fg1_w1 = (const float*)d_in[19], *fg1_b1 = (const float*)d_in[20];
    const float* fg1_w2 = (const float*)d_in[21], *fg1_b2 = (const float*)d_in[22];
    const float* ff_w1  = (const float*)d_in[23], *ff_b1  = (const float*)d_in[24];
    const float* ff_w2  = (const float*)d_in[25], *ff_b2  = (const float*)d_in[26];
    const float* ff1_w1 = (const float*)d_in[27], *ff1_b1 = (const float*)d_in[28];
    const float* ff1_w2 = (const float*)d_in[29], *ff1_b2 = (const float*)d_in[30];

    const int N1 = in_sizes[1] / 93;
    const int E1 = in_sizes[2] / 2;
    const int N2 = in_sizes[4] / 43;
    const int E2 = in_sizes[5] / 2;

    float* out = (float*)d_out;
    float* z   = out;
    float* xg  = out + 256;
    float* xg1 = out + 256 + 256 * 512;
    float* z1  = out + 256 + 2 * 256 * 512;

    char* wsb = (char*)d_ws;
    size_t off = 0;
    auto carve = [&](size_t bytes) {
        void* ptr = wsb + off;
        off = (off + bytes + 255) & ~(size_t)255;
        return ptr;
    };
    unsigned short* xb1  = (unsigned short*)carve((size_t)N1 * 96 * 2);  // also pm1/ps1
    unsigned short* xb2  = (unsigned short*)carve((size_t)N2 * 64 * 2);  // also pm2/ps2
    unsigned short* vb1  = (unsigned short*)carve((size_t)(N1 + 64) * 96 * 2);
    unsigned short* vb2  = (unsigned short*)carve((size_t)(N2 + 64) * 64 * 2);
    unsigned short* h1b1 = (unsigned short*)carve((size_t)N1 * 96 * 2);
    unsigned short* h1b2 = (unsigned short*)carve((size_t)N2 * 64 * 2);
    short* pb1  = (short*)carve((size_t)NG * 2048 * 2);
    short* pb2  = (short*)carve((size_t)NG * 1024 * 2);
    short* t1b1 = (short*)carve((size_t)NG * 1024 * 2);
    short* t1b2 = (short*)carve((size_t)NG * 1024 * 2);
    short* xgb1 = (short*)carve((size_t)NG * 512 * 2);
    short* xgb2 = (short*)carve((size_t)NG * 512 * 2);
    float* partial1 = (float*)carve((size_t)4 * 256 * 1024 * 4);
    float* partial2 = (float*)carve((size_t)4 * 256 * 1024 * 4);
    short* Wbl1 = (short*)carve((size_t)96 * 96 * 2);
    short* Wbg1 = (short*)carve((size_t)944 * 96 * 2);
    short* Wbl2 = (short*)carve((size_t)64 * 64 * 2);
    short* Wbg2 = (short*)carve((size_t)432 * 64 * 2);
    short* Wb1a = (short*)carve((size_t)1024 * 2048 * 2);
    short* Wb2a = (short*)carve((size_t)512 * 1024 * 2);
    short* Wb3a = (short*)carve((size_t)256 * 512 * 2);
    short* Wb1b = (short*)carve((size_t)1024 * 1024 * 2);
    short* Wb2b = (short*)carve((size_t)512 * 1024 * 2);
    short* Wb3b = (short*)carve((size_t)256 * 512 * 2);
    int* offs1 = (int*)carve(257 * 4);
    int* offs2 = (int*)carve(257 * 4);
    int* deg   = (int*)carve((size_t)(N1 + N2) * 4);
    int* rowoff1 = (int*)carve((size_t)(N1 + 1) * 4);
    int* rowoff2 = (int*)carve((size_t)(N2 + 1) * 4);
    int* cursor1 = (int*)carve((size_t)N1 * 4);
    int* cursor2 = (int*)carve((size_t)N2 * 4);
    int* csr1  = (int*)carve((size_t)E1 * 4);
    int* csr2  = (int*)carve((size_t)E2 * 4);
    int* bsum  = (int*)carve(256 * 4);
    int* deg1 = deg, *deg2 = deg + N1;
    int* bsum1 = bsum, *bsum2 = bsum + 128;
    float* pm1 = (float*)xb1;                    // xb dead after gather1
    float* ps1 = pm1 + (size_t)NG * 2 * 930;
    float* pm2 = (float*)xb2;
    float* ps2 = pm2 + (size_t)NG * 2 * 430;

    constexpr int KS = 4;

    // ---- prologue: repacks + fused cast/deg-zero/offs + windowed CSR -----
    RJobs10 jobs = {{
        { W1,     Wbl1, 93,   93,   96,   96   },
        { W2,     Wbg1, 93,   930,  944,  96   },
        { W3,     Wbl2, 43,   43,   64,   64   },
        { W4,     Wbg2, 43,   430,  432,  64   },
        { fg_w1,  Wb1a, 1860, 1024, 1024, 2048 },
        { fg_w2,  Wb2a, 1024, 512,  512,  1024 },
        { ff_w1,  Wb3a, 512,  256,  256,  512  },
        { fg1_w1, Wb1b, 860,  1024, 1024, 1024 },
        { fg1_w2, Wb2b, 1024, 512,  512,  1024 },
        { ff1_w1, Wb3b, 512,  256,  256,  512  },
    }};
    repack_all_kernel<<<dim3(512, 10), 256, 0, stream>>>(jobs);
    int castB1 = cdiv(N1 * 96, 256), castB2 = cdiv(N2 * 64, 256);
    int degB = cdiv(N1 + N2, 256);
    prologue_kernel<<<castB1 + castB2 + degB + 2, 256, 0, stream>>>(
        x, xb1, N1, a, xb2, N2, batch, offs1, c, offs2, deg, castB1, castB2, degB);
    int nwb1 = cdiv(E1, CHK) * 8, nwb2 = cdiv(E2, CHK) * 8;
    deg_win_both_kernel<<<nwb1 + nwb2, 256, 0, stream>>>(ei, E1, N1, deg1, nwb1,
                                                         ed, E2, N2, deg2);
    int nb1 = cdiv(N1, 1024), nb2 = cdiv(N2, 1024);
    scan1_both_kernel<<<nb1 + nb2, 256, 0, stream>>>(deg1, N1, rowoff1, bsum1, nb1,
                                                     deg2, N2, rowoff2, bsum2);
    int nc1 = cdiv(N1, 256), nc2 = cdiv(N2, 256);
    scan3_both_kernel<<<nc1 + nc2, 256, 0, stream>>>(rowoff1, bsum1, cursor1, N1, E1, nb1,
                                                     rowoff2, bsum2, cursor2, N2, E2, nc1);
    fill_win_both_kernel<<<nwb1 + nwb2, 256, 0, stream>>>(ei, E1, N1, cursor1, csr1, nwb1,
                                                          ed, E2, N2, cursor2, csr2);

    // ---- merged GIN chains (vb = self + neighbor sum, bf16 rows) ---------
    int ng1 = cdiv(N1, 4), ng2 = cdiv(N2, 4);
    gather_both_kernel<<<ng1 + ng2, 256, 0, stream>>>(
        xb1, csr1, rowoff1, vb1, N1, ng1, xb2, csr2, rowoff2, vb2, N2);
    int nl1 = cdiv(N1, 64), nl2 = cdiv(N2, 64);
    gin_linear_both_kernel<<<nl1 + nl2, 256, 0, stream>>>(
        vb1, Wbl1, b1, h1b1, N1, nl1, vb2, Wbl2, b3, h1b2, N2);
    gather_both_kernel<<<ng1 + ng2, 256, 0, stream>>>(
        h1b1, csr1, rowoff1, vb1, N1, ng1, h1b2, csr2, rowoff2, vb2, N2);
    gin_pool_both_kernel<<<NG * 2 * 2, 256, 0, stream>>>(
        vb1, Wbg1, b2, offs1, pm1, ps1, NG * 2,
        vb2, Wbg2, b4, offs2, pm2, ps2);
    pool_reduce_both_kernel<<<2 * NG, 256, 0, stream>>>(
        pm1, ps1, offs1, pb1, pm2, ps2, offs2, pb2);

    // ---- merged FC stack (KS=4 split-K) ----------------------------------
    fc_mfma_both_kernel<512, 256><<<512, 256, 0, stream>>>(
        pb1, Wb1a, partial1, 2048, 16, 256, pb2, Wb1b, partial2, 1024, 16);
    fc_reduce_both_kernel<KS, true, true, false><<<cdiv(2 * 256 * 1024, 256), 256, 0, stream>>>(
        partial1, fg_b1, t1b1, nullptr, 256 * 1024, 1024,
        partial2, fg1_b1, t1b2, nullptr, 256 * 1024, 1024);
    fc_mfma_both_kernel<256, 256><<<256, 256, 0, stream>>>(
        t1b1, Wb2a, partial1, 1024, 8, 128, t1b2, Wb2b, partial2, 1024, 8);
    fc_reduce_both_kernel<KS, false, true, true><<<cdiv(2 * 256 * 512, 256), 256, 0, stream>>>(
        partial1, fg_b2, xgb1, xg, 256 * 512, 512,
        partial2, fg1_b2, xgb2, xg1, 256 * 512, 512);
    fc_mfma_both_kernel<128, 128><<<128, 256, 0, stream>>>(
        xgb1, Wb3a, partial1, 512, 4, 64, xgb2, Wb3b, partial2, 512, 4);
    head_final_both_kernel<KS><<<512, 256, 0, stream>>>(
        partial1, ff_b1, ff_w2, ff_b2, z,
        partial2, ff1_b1, ff1_w2, ff1_b2, z1);
}